// Round 14
// baseline (994.782 us; speedup 1.0000x reference)
//
#include <hip/hip_runtime.h>
#include <stdint.h>

#define N_TOK   65536
#define MDIM    2048
#define FDIM    512
#define SCALE_F 10.0f
#define TAU_BF  1.2e-3f   // level-1: bf16-S ambiguity (~9 sigma)
#define TAU_SP  2e-5f     // level-2: split-S ambiguity (~100 sigma)
#define QCAP    8192

typedef __attribute__((ext_vector_type(8))) unsigned short u16x8;
typedef __attribute__((ext_vector_type(4))) unsigned short u16x4;
typedef __attribute__((ext_vector_type(8))) __bf16 bf16x8;
typedef __attribute__((ext_vector_type(4))) float f32x4;

__device__ __forceinline__ unsigned short f2bf(float f) {
  unsigned int u = __builtin_bit_cast(unsigned int, f);
  u += 0x7fffu + ((u >> 16) & 1u);   // round-to-nearest-even
  return (unsigned short)(u >> 16);
}
__device__ __forceinline__ float bf2f(unsigned short b) {
  return __builtin_bit_cast(float, (unsigned int)b << 16);
}
__device__ __forceinline__ f32x4 mfma16(u16x8 a, u16x8 b, f32x4 c) {
  return __builtin_amdgcn_mfma_f32_16x16x32_bf16(
      __builtin_bit_cast(bf16x8, a), __builtin_bit_cast(bf16x8, b), c, 0, 0, 0);
}
__device__ __forceinline__ void gload16(const unsigned short* g, unsigned short* l) {
  __builtin_amdgcn_global_load_lds(
      (const __attribute__((address_space(1))) unsigned int*)g,
      (__attribute__((address_space(3))) unsigned int*)l,
      16, 0, 0);
}
// order-preserving float->u32; tie -> smaller col wins (np.argmax)
__device__ __forceinline__ unsigned long long packkey(float x, int col) {
  unsigned u = __builtin_bit_cast(unsigned, x);
  u = (u & 0x80000000u) ? ~u : (u | 0x80000000u);
  return ((unsigned long long)u << 32) | (unsigned)(2048 - col);
}
__device__ __forceinline__ float unpackval(unsigned long long k) {
  unsigned u = (unsigned)(k >> 32);
  u = (u & 0x80000000u) ? (u & 0x7fffffffu) : ~u;
  return __builtin_bit_cast(float, u);
}
__device__ __forceinline__ int unpackcol(unsigned long long k) {
  return 2048 - (int)(k & 0xffffffffu);
}
__device__ __forceinline__ void merge2(unsigned long long& k1, unsigned long long& k2,
                                       unsigned long long o1, unsigned long long o2) {
  if (o1 > k1) { k2 = (k1 > o2) ? k1 : o2; k1 = o1; }
  else if (o1 > k2) { k2 = o1; }
}

// ---------------- zero queue counter ----------------
__global__ __launch_bounds__(64) void zero_k(int* __restrict__ qcount) {
  if (threadIdx.x == 0) *qcount = 0;
}

// ---------------- memory_norm -> bf16 hi/lo ----------------
__global__ __launch_bounds__(64) void prep_memory_k(
    const float* __restrict__ mem, unsigned short* __restrict__ Bh,
    unsigned short* __restrict__ Bl) {
  const int m = blockIdx.x;
  const int lane = threadIdx.x;
  const float* row = mem + (size_t)m * FDIM;
  float4 a = *(const float4*)(row + lane * 4);
  float4 b = *(const float4*)(row + 256 + lane * 4);
  float s = a.x * a.x + a.y * a.y + a.z * a.z + a.w * a.w +
            b.x * b.x + b.y * b.y + b.z * b.z + b.w * b.w;
  #pragma unroll
  for (int off = 1; off < 64; off <<= 1) s += __shfl_xor(s, off);
  const float rn = 1.0f / sqrtf(fmaxf(s, 1e-12f));
  float v[8] = {a.x, a.y, a.z, a.w, b.x, b.y, b.z, b.w};
  #pragma unroll
  for (int h = 0; h < 2; ++h) {
    ushort4 hs, lo;
    #pragma unroll
    for (int q = 0; q < 4; ++q) {
      float x = v[h * 4 + q] * rn;
      unsigned short hb = f2bf(x);
      ((unsigned short*)&hs)[q] = hb;
      ((unsigned short*)&lo)[q] = f2bf(x - bf2f(hb));
    }
    const size_t e = (size_t)m * FDIM + h * 256 + lane * 4;
    *(ushort4*)(Bh + e) = hs;
    *(ushort4*)(Bl + e) = lo;
  }
}

// ---------------- transpose Bh [M][F] -> Bt [F][M] ----------------
__global__ __launch_bounds__(256) void transpose_k(
    const unsigned short* __restrict__ Bh, unsigned short* __restrict__ Bt) {
  __shared__ unsigned short t[32][33];
  const int m0 = blockIdx.x * 32, f0 = blockIdx.y * 32;
  const int tx = threadIdx.x & 31, ty = threadIdx.x >> 5;
  #pragma unroll
  for (int r = ty; r < 32; r += 8)
    t[r][tx] = Bh[(size_t)(m0 + r) * FDIM + f0 + tx];
  __syncthreads();
  #pragma unroll
  for (int r = ty; r < 32; r += 8)
    Bt[(size_t)(f0 + r) * MDIM + m0 + tx] = t[tx][r];
}

// ------- fused: input row inv-norm + inputs_norm -> bf16 (one pass) -------
__global__ __launch_bounds__(256) void prep_a_k(
    const float* __restrict__ inp, float* __restrict__ inv_n,
    unsigned short* __restrict__ Ah, int baseRow) {
  const int r = blockIdx.x * 4 + (threadIdx.x >> 6);   // chunk-local row
  const int lane = threadIdx.x & 63;
  const int grow = baseRow + r;
  const float* x = inp + (size_t)grow * FDIM;
  float4 a = *(const float4*)(x + lane * 4);
  float4 b = *(const float4*)(x + 256 + lane * 4);
  float s = a.x * a.x + a.y * a.y + a.z * a.z + a.w * a.w +
            b.x * b.x + b.y * b.y + b.z * b.z + b.w * b.w;
  #pragma unroll
  for (int off = 1; off < 64; off <<= 1) s += __shfl_xor(s, off);
  const float rn = 1.0f / sqrtf(fmaxf(s, 1e-12f));
  if (lane == 0) inv_n[grow] = rn;
  ushort4 h0, h1;
  h0.x = f2bf(a.x * rn); h0.y = f2bf(a.y * rn);
  h0.z = f2bf(a.z * rn); h0.w = f2bf(a.w * rn);
  h1.x = f2bf(b.x * rn); h1.y = f2bf(b.y * rn);
  h1.z = f2bf(b.z * rn); h1.w = f2bf(b.w * rn);
  *(ushort4*)(Ah + (size_t)r * FDIM + lane * 4) = h0;
  *(ushort4*)(Ah + (size_t)r * FDIM + 256 + lane * 4) = h1;
}

// ====== persistent 8-phase 256-wide GEMM: C = A * B^T (B row-major [N][K]) ======
// 512 thr (8 waves 2Mx4N), BK=64, 2 K-tiles/iter. Tile stream T=0..SEGS*NTSEG-1:
// n0=(T>>NTL)*256 (or fixed bx for SEGS=1), koff=(T&(NTSEG-1))*64. Pipeline never
// drains across segments. MODE 1: per-segment epilogue into separate 16KB scratch
// (P=bf16(exp(10*s)) + sidecar esum/top2), acc reset. MODE 2: C=acc*rowinv at end.
template <int MODE, int SEGS, int NTL>
__global__ __launch_bounds__(512) void gemm8p_k(
    const unsigned short* __restrict__ Am, const unsigned short* __restrict__ Bm,
    void* __restrict__ Cv, int N, int K, int nbxLog2,
    float* __restrict__ ssum, unsigned long long* __restrict__ sk1,
    unsigned long long* __restrict__ sk2, const float* __restrict__ rowinv) {
  constexpr int NTSEG = 1 << NTL;
  constexpr int NTT = SEGS * NTSEG;
  constexpr int NITER = NTT / 2;
  __shared__ alignas(16) char smem[(MODE == 1) ? 147456 : 131072];
  int wg = blockIdx.x;
  { const int q = gridDim.x >> 3; wg = (wg & 7) * q + (wg >> 3); }  // XCD swizzle
  int by, bx0 = 0;
  if constexpr (SEGS > 1) { by = wg; }
  else { bx0 = wg & ((1 << nbxLog2) - 1); by = wg >> nbxLog2; }
  const int m0 = by * 256;
  const int tid = threadIdx.x;
  const int lane = tid & 63, wid = tid >> 6;
  const int wm = wid >> 2, wn = wid & 3;
  const int lr = lane & 15, ls = lane >> 4;
  const int c16 = (lane & 7) ^ (lane >> 3);   // inverse-swizzled source slot
  const int lrow8 = lane >> 3;

  f32x4 acc[8][4] = {};
  u16x8 bF[4][2];

  auto stageB = [&](int T, int half) {   // 2 chunks/wave (16KB unit)
    const int n0 = (SEGS > 1 ? (T >> NTL) : bx0) * 256;
    const int ko = (T & (NTSEG - 1)) * 64;
    char* dst0 = smem + (T & 1) * 65536 + 32768 + half * 16384;
    #pragma unroll
    for (int c = 0; c < 2; ++c) {
      const int R = (wid * 2 + c) * 8;
      const int rg = n0 + half * 128 + R + lrow8;
      gload16(Bm + (size_t)rg * K + ko + c16 * 8,
              (unsigned short*)(dst0 + R * 128));
    }
  };
  auto stageA = [&](int T, int q) {      // 1 chunk/wave (8KB unit, rows q*32..+32)
    const int ko = (T & (NTSEG - 1)) * 64;
    const int half = wid >> 2;
    const int R = q * 32 + (wid & 3) * 8;
    char* dst = smem + (T & 1) * 65536 + half * 16384 + R * 128;
    const int rg = m0 + half * 128 + R + lrow8;
    gload16(Am + (size_t)rg * K + ko + c16 * 8, (unsigned short*)dst);
  };
  auto ldsA = [&](int b, int rl, int ks) -> u16x8 {
    const int p = (ks * 4 + ls) ^ (rl & 7);
    return *(const u16x8*)(smem + b * 65536 + wm * 16384 + rl * 128 + p * 16);
  };
  auto ldsB = [&](int b, int rlb, int ks) -> u16x8 {
    const int half = rlb >> 7, rl = rlb & 127;
    const int p = (ks * 4 + ls) ^ (rl & 7);
    return *(const u16x8*)(smem + b * 65536 + 32768 + half * 16384 + rl * 128 + p * 16);
  };

  // prologue: tile0 full (8 loads), tile1 minus A-unit3 (7 loads)
  stageB(0, 0); stageB(0, 1);
  stageA(0, 0); stageA(0, 1); stageA(0, 2); stageA(0, 3);
  stageB(1, 0); stageB(1, 1);
  stageA(1, 0); stageA(1, 1); stageA(1, 2);

  for (int it = 0; it < NITER; ++it) {
    const int T0 = 2 * it, T1 = T0 + 1;
    #pragma unroll
    for (int ph = 0; ph < 8; ++ph) {
      const int tb = (ph < 4) ? 0 : 1;       // buffer = tile parity (T0 even)
      const int ql = ph & 3;
      if (ql == 0) {
        if (ph == 4 && it == NITER - 1)
          asm volatile("s_waitcnt vmcnt(0)" ::: "memory");  // tail: no trailing loads
        else
          asm volatile("s_waitcnt vmcnt(7)" ::: "memory");  // tile's 8 chunks landed
        __builtin_amdgcn_sched_barrier(0);
        __builtin_amdgcn_s_barrier();
        #pragma unroll
        for (int nj = 0; nj < 4; ++nj)
          #pragma unroll
          for (int ks = 0; ks < 2; ++ks)
            bF[nj][ks] = ldsB(tb, wn * 64 + nj * 16 + lr, ks);
      } else {
        __builtin_amdgcn_s_barrier();
      }
      u16x8 aF[2][2];
      #pragma unroll
      for (int di = 0; di < 2; ++di)
        #pragma unroll
        for (int ks = 0; ks < 2; ++ks)
          aF[di][ks] = ldsA(tb, ql * 32 + di * 16 + lr, ks);
      // staging schedule (region died last phase -> safe to overwrite now)
      if (ph == 0) { if (T1 < NTT) stageA(T1, 3); }
      if (ph == 1) { if (T0 + 2 < NTT) stageB(T0 + 2, 0); }
      if (ph == 2) { if (T0 + 2 < NTT) { stageB(T0 + 2, 1); stageA(T0 + 2, 0); } }
      if (ph == 3) { if (T0 + 2 < NTT) { stageA(T0 + 2, 1); stageA(T0 + 2, 2); } }
      if (ph == 4) { if (T0 + 2 < NTT) stageA(T0 + 2, 3); }
      if (ph == 5) { if (T1 + 2 < NTT) stageB(T1 + 2, 0); }
      if (ph == 6) { if (T1 + 2 < NTT) { stageB(T1 + 2, 1); stageA(T1 + 2, 0); } }
      if (ph == 7) { if (T1 + 2 < NTT) { stageA(T1 + 2, 1); stageA(T1 + 2, 2); } }
      __builtin_amdgcn_s_setprio(1);
      #pragma unroll
      for (int di = 0; di < 2; ++di)
        #pragma unroll
        for (int nj = 0; nj < 4; ++nj)
          #pragma unroll
          for (int ks = 0; ks < 2; ++ks)
            acc[ql * 2 + di][nj] = mfma16(aF[di][ks], bF[nj][ks], acc[ql * 2 + di][nj]);
      __builtin_amdgcn_s_setprio(0);
      __builtin_amdgcn_s_barrier();          // barrier-B: region discipline
    }
    if constexpr (MODE == 1) {
      if (((it + 1) & ((NTSEG >> 1) - 1)) == 0) {   // end of N-segment
        const int seg = it >> (NTL - 1);
        const int n0e = seg * 256;
        float* sc = (float*)(smem + 131072);        // [16][64 slots] swizzled
        unsigned short* P = (unsigned short*)Cv;
        #pragma unroll
        for (int g = 0; g < 16; ++g) {
          __syncthreads();
          if (wm == (g >> 3)) {                     // 4 waves dump mi = g&7
            const int mi = g & 7;
            #pragma unroll
            for (int nj = 0; nj < 4; ++nj)
              #pragma unroll
              for (int q = 0; q < 4; ++q) {
                const int row = ls * 4 + q;         // 0..15 within group
                const int col = wn * 64 + nj * 16 + lr;
                sc[row * 256 + (((col >> 2) ^ (row & 7)) * 4) + (col & 3)] =
                    acc[mi][nj][q];
              }
          }
          __syncthreads();
          const int r = tid >> 5, cs = tid & 31;    // 16 rows x 32 threads/row
          const int grow = m0 + g * 16 + r;
          float esum = 0.f, m1v = -3.4e38f, m2v = -3.4e38f;
          int c1 = 0;
          unsigned short pk[8];
          #pragma unroll
          for (int k = 0; k < 2; ++k) {
            const int slot = k * 32 + cs;           // cols ascending in k
            const f32x4 v = *(const f32x4*)&sc[r * 256 + ((slot ^ (r & 7)) * 4)];
            #pragma unroll
            for (int e = 0; e < 4; ++e) {
              const float s = v[e];
              const int col = n0e + slot * 4 + e;
              if (s > m1v) { m2v = m1v; m1v = s; c1 = col; }
              else if (s > m2v) m2v = s;
              const float ex = __expf(SCALE_F * s);
              esum += ex;
              pk[k * 4 + e] = f2bf(ex);
            }
          }
          *(u16x4*)&P[(size_t)grow * N + n0e + cs * 4] = *(u16x4*)&pk[0];
          *(u16x4*)&P[(size_t)grow * N + n0e + 128 + cs * 4] = *(u16x4*)&pk[4];
          unsigned long long k1 = packkey(m1v, c1);
          unsigned long long k2 = packkey(m2v, 2047);
          #pragma unroll
          for (int off = 1; off < 32; off <<= 1) {  // merge 32 threads of the row
            const unsigned long long o1 = __shfl_xor(k1, off);
            const unsigned long long o2 = __shfl_xor(k2, off);
            esum += __shfl_xor(esum, off);
            merge2(k1, k2, o1, o2);
          }
          if (cs == 0) {
            const size_t sp = (size_t)grow * 8 + seg;
            ssum[sp] = esum; sk1[sp] = k1; sk2[sp] = k2;
          }
        }
        #pragma unroll
        for (int mi = 0; mi < 8; ++mi)
          #pragma unroll
          for (int nj = 0; nj < 4; ++nj)
            acc[mi][nj] = (f32x4){0.f, 0.f, 0.f, 0.f};
      }
    }
  }

  if constexpr (MODE == 2) {
    float* C = (float*)Cv;
    const int n0 = bx0 * 256;
    #pragma unroll
    for (int mi = 0; mi < 8; ++mi) {
      const int rbase = m0 + wm * 128 + mi * 16 + ls * 4;
      #pragma unroll
      for (int q = 0; q < 4; ++q) {
        const float ri = rowinv[rbase + q];
        #pragma unroll
        for (int nj = 0; nj < 4; ++nj) {
          const int col = n0 + wn * 64 + nj * 16 + lr;
          C[(size_t)(rbase + q) * N + col] = acc[mi][nj][q] * ri;
        }
      }
    }
  }
}

// ---- refine split-GEMM (proven 128x128 dbuf kernel, hi/lo compensation) ----
__global__ __launch_bounds__(256) void gemm_ref_k(
    const unsigned short* __restrict__ Ah, const unsigned short* __restrict__ Al,
    const unsigned short* __restrict__ Bh, const unsigned short* __restrict__ Bl,
    float* __restrict__ C, int N, int K, int nbxLog2,
    const int* __restrict__ qlimit) {
  const int wg = blockIdx.x;
  const int bx = wg & ((1 << nbxLog2) - 1);
  const int by = wg >> nbxLog2;
  const int m0 = by * 128, n0 = bx * 128;
  {
    int lim = *qlimit; if (lim > QCAP) lim = QCAP;
    lim = (lim + 127) & ~127;
    if (m0 >= lim) return;
  }
  constexpr int BUF_B = 4 * 8192;
  __shared__ alignas(16) char smem[2 * BUF_B];

  const int tid = threadIdx.x;
  const int lane = tid & 63, wave = tid >> 6;
  const int wr = wave >> 1, wc = wave & 1;
  const int lr = lane & 15, ls = lane >> 4;

  f32x4 acc[4][4] = {};

  const int row0 = wave * 32 + (lane >> 2);
  const int row1 = row0 + 16;
  const int ce = (lane & 3) * 8;
  const unsigned short* gA0 = Ah + (size_t)(m0 + row0) * K + ce;
  const unsigned short* gA1 = Ah + (size_t)(m0 + row1) * K + ce;
  const unsigned short* gB0 = Bh + (size_t)(n0 + row0) * K + ce;
  const unsigned short* gB1 = Bh + (size_t)(n0 + row1) * K + ce;
  const unsigned short* gAl0 = Al + (size_t)(m0 + row0) * K + ce;
  const unsigned short* gAl1 = Al + (size_t)(m0 + row1) * K + ce;
  const unsigned short* gBl0 = Bl + (size_t)(n0 + row0) * K + ce;
  const unsigned short* gBl1 = Bl + (size_t)(n0 + row1) * K + ce;

  auto stage = [&](int buf) {
    char* sb = smem + buf * BUF_B;
    unsigned short* bAh = (unsigned short*)sb;
    unsigned short* bBh = (unsigned short*)(sb + 8192);
    unsigned short* bAl = (unsigned short*)(sb + 16384);
    unsigned short* bBl = (unsigned short*)(sb + 24576);
    gload16(gA0, &bAh[wave * 1024]); gload16(gA1, &bAh[wave * 1024 + 512]);
    gload16(gB0, &bBh[wave * 1024]); gload16(gB1, &bBh[wave * 1024 + 512]);
    gload16(gAl0, &bAl[wave * 1024]); gload16(gAl1, &bAl[wave * 1024 + 512]);
    gload16(gBl0, &bBl[wave * 1024]); gload16(gBl1, &bBl[wave * 1024 + 512]);
    gA0 += 32; gA1 += 32; gB0 += 32; gB1 += 32;
    gAl0 += 32; gAl1 += 32; gBl0 += 32; gBl1 += 32;
  };

  const int nk = K >> 5;
  stage(0);
  __syncthreads();
  for (int ks = 0; ks < nk; ++ks) {
    const int cur = ks & 1;
    if (ks + 1 < nk) stage(cur ^ 1);
    const char* sb = smem + cur * BUF_B;
    u16x8 fa[4], fb[4], fal[4], fbl[4];
    #pragma unroll
    for (int i = 0; i < 4; ++i) {
      const int ra = (wr * 64 + i * 16 + lr) * 32 + ls * 8;
      const int rb = (wc * 64 + i * 16 + lr) * 32 + ls * 8;
      fa[i] = *(const u16x8*)&((const unsigned short*)sb)[ra];
      fb[i] = *(const u16x8*)&((const unsigned short*)(sb + 8192))[rb];
      fal[i] = *(const u16x8*)&((const unsigned short*)(sb + 16384))[ra];
      fbl[i] = *(const u16x8*)&((const unsigned short*)(sb + 24576))[rb];
    }
    #pragma unroll
    for (int i = 0; i < 4; ++i)
      #pragma unroll
      for (int j = 0; j < 4; ++j) {
        acc[i][j] = mfma16(fa[i], fb[j], acc[i][j]);
        acc[i][j] = mfma16(fal[i], fb[j], acc[i][j]);
        acc[i][j] = mfma16(fa[i], fbl[j], acc[i][j]);
      }
    __syncthreads();
  }

  #pragma unroll
  for (int i = 0; i < 4; ++i) {
    const int rrow = m0 + wr * 64 + i * 16 + ls * 4;
    #pragma unroll
    for (int j = 0; j < 4; ++j) {
      const int col = n0 + wc * 64 + j * 16 + lr;
      #pragma unroll
      for (int q = 0; q < 4; ++q)
        C[(size_t)(rrow + q) * N + col] = acc[i][j][q];
    }
  }
}

// ------- merge 8 sidecar partials per row: idx, rowinv, queue -------
__global__ __launch_bounds__(256) void rowstat_k(
    const float* __restrict__ ssum, const unsigned long long* __restrict__ sk1,
    const unsigned long long* __restrict__ sk2, int* __restrict__ idx,
    float* __restrict__ rowinv, int* __restrict__ queue,
    int* __restrict__ qcount, int baseRow) {
  const int row = blockIdx.x * 32 + (threadIdx.x >> 3);
  const int p = threadIdx.x & 7;
  const size_t sp = (size_t)row * 8 + p;
  float sum = ssum[sp];
  unsigned long long k1 = sk1[sp], k2 = sk2[sp];
  #pragma unroll
  for (int off = 1; off < 8; off <<= 1) {
    const unsigned long long o1 = __shfl_xor(k1, off);
    const unsigned long long o2 = __shfl_xor(k2, off);
    sum += __shfl_xor(sum, off);
    merge2(k1, k2, o1, o2);
  }
  if (p == 0) {
    const int tok = baseRow + row;
    idx[tok] = unpackcol(k1);
    rowinv[row] = 1.0f / sum;
    if (unpackval(k1) - unpackval(k2) < TAU_BF) {
      int slot = atomicAdd(qcount, 1);
      if (slot < QCAP) queue[slot] = tok;
    }
  }
}

// ------- gather queued tokens' normalized rows -> compact hi/lo matrix -------
__global__ __launch_bounds__(256) void gather_prep_k(
    const int* __restrict__ queue, const int* __restrict__ qcount,
    const float* __restrict__ inp, const float* __restrict__ inv_n,
    unsigned short* __restrict__ Qh, unsigned short* __restrict__ Ql) {
  const int w = blockIdx.x * 4 + (threadIdx.x >> 6);
  const int lane = threadIdx.x & 63;
  int cnt = *qcount; if (cnt > QCAP) cnt = QCAP;
  if (w >= cnt) return;
  const int tok = queue[w];
  const float rn = inv_n[tok];
  const float* x = inp + (size_t)tok * FDIM;
  #pragma unroll
  for (int h = 0; h < 2; ++h) {
    float4 xv = *(const float4*)(x + h * 256 + lane * 4);
    float vv[4] = {xv.x, xv.y, xv.z, xv.w};
    ushort4 hs, lo;
    #pragma unroll
    for (int q = 0; q < 4; ++q) {
      float v = vv[q] * rn;
      unsigned short hb = f2bf(v);
      ((unsigned short*)&hs)[q] = hb;
      ((unsigned short*)&lo)[q] = f2bf(v - bf2f(hb));
    }
    const size_t e = (size_t)w * FDIM + h * 256 + lane * 4;
    *(ushort4*)(Qh + e) = hs;
    *(ushort4*)(Ql + e) = lo;
  }
}

// ------- level-2: full-row top-2 on split-S; fp64 pair-decide; write idx -------
__global__ __launch_bounds__(256) void refine2_k(
    const int* __restrict__ queue, const int* __restrict__ qcount,
    const float* __restrict__ Sref, const float* __restrict__ inp,
    const float* __restrict__ mem, int* __restrict__ idx) {
  const int w = blockIdx.x * 4 + (threadIdx.x >> 6);
  const int lane = threadIdx.x & 63;
  int cnt = *qcount; if (cnt > QCAP) cnt = QCAP;
  if (w >= cnt) return;
  const int tok = queue[w];
  const float* srow = Sref + (size_t)w * MDIM;
  float m1 = -3.4e38f, m2 = -3.4e38f;
  int i1 = 0x7fffffff, i2 = 0x7fffffff;
  #pragma unroll
  for (int i = 0; i < 8; ++i) {
    const float4 vv = *(const float4*)(srow + i * 256 + lane * 4);
    const float xs[4] = {vv.x, vv.y, vv.z, vv.w};
    #pragma unroll
    for (int q = 0; q < 4; ++q) {
      const float x = xs[q];
      const int ii = i * 256 + lane * 4 + q;
      if (x > m1 || (x == m1 && ii < i1)) { m2 = m1; i2 = i1; m1 = x; i1 = ii; }
      else if (x > m2 || (x == m2 && ii < i2)) { m2 = x; i2 = ii; }
    }
  }
  #pragma unroll
  for (int off = 1; off < 64; off <<= 1) {
    const float n1 = __shfl_xor(m1, off), n2 = __shfl_xor(m2, off);
    const int j1 = __shfl_xor(i1, off), j2 = __shfl_xor(i2, off);
    if (n1 > m1 || (n1 == m1 && j1 < i1)) {
      if (m1 > n2 || (m1 == n2 && i1 < j2)) { m2 = m1; i2 = i1; }
      else { m2 = n2; i2 = j2; }
      m1 = n1; i1 = j1;
    } else if (n1 > m2 || (n1 == m2 && j1 < i2)) { m2 = n1; i2 = j1; }
  }
  int pick = i1;
  if (m1 - m2 < TAU_SP) {
    const int a = (i1 < i2) ? i1 : i2, b = (i1 < i2) ? i2 : i1;
    const float* x = inp + (size_t)tok * FDIM;
    const float* ma = mem + (size_t)a * FDIM;
    const float* mb = mem + (size_t)b * FDIM;
    double da = 0, db = 0, na = 0, nb = 0;
    #pragma unroll
    for (int j = 0; j < 8; ++j) {
      const int e = lane * 8 + j;
      const double xv = x[e], av = ma[e], bv = mb[e];
      da += xv * av; na += av * av;
      db += xv * bv; nb += bv * bv;
    }
    #pragma unroll
    for (int off = 1; off < 64; off <<= 1) {
      da += __shfl_xor(da, off); na += __shfl_xor(na, off);
      db += __shfl_xor(db, off); nb += __shfl_xor(nb, off);
    }
    const double d1 = da / sqrt(fmax(na, 1e-12));
    const double d2 = db / sqrt(fmax(nb, 1e-12));
    if (d2 > d1) pick = b;
    else pick = a;
  }
  if (lane == 0) idx[tok] = pick;
}

// ------- deterministic segment-sum: one block per code, no atomics -------
__global__ __launch_bounds__(256) void segsum_k(
    const int* __restrict__ idx, const float* __restrict__ inp,
    const float* __restrict__ inv_n, float* __restrict__ updates) {
  __shared__ int lst[256];
  __shared__ int lcnt;
  const int m = blockIdx.x;
  const int t = threadIdx.x;
  float a0 = 0.f, a1 = 0.f;
  for (int base = 0; base < N_TOK; base += 4096) {
    if (t == 0) lcnt = 0;
    __syncthreads();
    #pragma unroll
    for (int u = 0; u < 4; ++u) {
      const int off4 = (u * 256 + t) * 4;
      const int4 v = *(const int4*)&idx[base + off4];
      if (v.x == m) { int p = atomicAdd(&lcnt, 1); if (p < 256) lst[p] = base + off4 + 0; }
      if (v.y == m) { int p = atomicAdd(&lcnt, 1); if (p < 256) lst[p] = base + off4 + 1; }
      if (v.z == m) { int p = atomicAdd(&lcnt, 1); if (p < 256) lst[p] = base + off4 + 2; }
      if (v.w == m) { int p = atomicAdd(&lcnt, 1); if (p < 256) lst[p] = base + off4 + 3; }
    }
    __syncthreads();
    int c = lcnt; if (c > 256) c = 256;
    if (t == 0 && c > 1) {
      for (int i = 1; i < c; ++i) {
        int key = lst[i], j = i - 1;
        while (j >= 0 && lst[j] > key) { lst[j + 1] = lst[j]; --j; }
        lst[j + 1] = key;
      }
    }
    __syncthreads();
    for (int i = 0; i < c; ++i) {
      const int tok = lst[i];
      const float rn = inv_n[tok];
      const float2 xv = *(const float2*)&inp[(size_t)tok * FDIM + t * 2];
      a0 += xv.x * rn; a1 += xv.y * rn;
    }
    __syncthreads();
  }
  *(float2*)&updates[(size_t)m * FDIM + t * 2] = make_float2(a0, a1);
}

// ---------------- final blend (fp32 out) ----------------
__global__ __launch_bounds__(256) void final_update_k(
    const float* __restrict__ mem, const float* __restrict__ upd,
    float* __restrict__ out) {
  const size_t i = ((size_t)blockIdx.x * 256 + threadIdx.x) * 4;
  float4 m = *(const float4*)(mem + i);
  float4 u = *(const float4*)(upd + i);
  float4 r;
  r.x = m.x * 0.9f + u.x * 0.1f;
  r.y = m.y * 0.9f + u.y * 0.1f;
  r.z = m.z * 0.9f + u.z * 0.1f;
  r.w = m.w * 0.9f + u.w * 0.1f;
  *(float4*)(out + i) = r;
}

extern "C" void kernel_launch(void* const* d_in, const int* in_sizes, int n_in,
                              void* d_out, int out_size, void* d_ws, size_t ws_size,
                              hipStream_t stream) {
  const float* inputs = (const float*)d_in[0];
  const float* memory = (const float*)d_in[1];
  if (n_in >= 2 && in_sizes[0] != N_TOK * FDIM) {  // order guard
    inputs = (const float*)d_in[1];
    memory = (const float*)d_in[0];
  }
  float* out_mu = (float*)d_out;                       // [N][F] fp32
  float* out_um = out_mu + (size_t)N_TOK * FDIM;       // [M][F] fp32

  char* base = (char*)d_ws;
  size_t off = 0;
  auto take = [&](size_t bytes) -> char* {
    char* p = base + off;
    off = (off + bytes + 255) & ~(size_t)255;
    return p;
  };
  unsigned short* Bh = (unsigned short*)take((size_t)MDIM * FDIM * 2);
  unsigned short* Bl = (unsigned short*)take((size_t)MDIM * FDIM * 2);
  unsigned short* Bt = (unsigned short*)take((size_t)MDIM * FDIM * 2);
  float* inv_n = (float*)take((size_t)N_TOK * 4);
  float* updates = (float*)take((size_t)MDIM * FDIM * 4);
  int* idx = (int*)take((size_t)N_TOK * 4);
  int* queue = (int*)take((size_t)QCAP * 4);
  int* qcount = (int*)take(256);
  unsigned short* Qh = (unsigned short*)take((size_t)QCAP * FDIM * 2);
  unsigned short* Ql = (unsigned short*)take((size_t)QCAP * FDIM * 2);
  float* Sref = (float*)take((size_t)QCAP * MDIM * 4);
  const size_t fixed = off;

  // per-token: Ah 1024 + P 4096 + sidecar 8*(4+8+8)=160 + rowinv 4
  int chunkT = 65536;  // single pass if ws allows
  while (chunkT > 2048 && fixed + (size_t)chunkT * 5400 + 8192 > ws_size)
    chunkT >>= 1;
  if (fixed + (size_t)chunkT * 5400 + 8192 > ws_size) return;  // ws too small

  unsigned short* Ah = (unsigned short*)take((size_t)chunkT * FDIM * 2);
  unsigned short* Pbuf = (unsigned short*)take((size_t)chunkT * MDIM * 2);
  float* ssum = (float*)take((size_t)chunkT * 8 * 4);
  unsigned long long* sk1 = (unsigned long long*)take((size_t)chunkT * 8 * 8);
  unsigned long long* sk2 = (unsigned long long*)take((size_t)chunkT * 8 * 8);
  float* rowinv = (float*)take((size_t)chunkT * 4);

  zero_k<<<1, 64, 0, stream>>>(qcount);
  prep_memory_k<<<MDIM, 64, 0, stream>>>(memory, Bh, Bl);
  transpose_k<<<dim3(MDIM / 32, FDIM / 32), 256, 0, stream>>>(Bh, Bt);

  for (int baseRow = 0; baseRow < N_TOK; baseRow += chunkT) {
    prep_a_k<<<chunkT / 4, 256, 0, stream>>>(inputs, inv_n, Ah, baseRow);
    // GEMM1: persistent 8-phase, 1 block per 256-row M-panel, 8 N-segments
    gemm8p_k<1, 8, 3><<<chunkT / 256, 512, 0, stream>>>(
        Ah, Bh, (void*)Pbuf, MDIM, FDIM, 0, ssum, sk1, sk2, nullptr);
    rowstat_k<<<chunkT / 32, 256, 0, stream>>>(
        ssum, sk1, sk2, idx, rowinv, queue, qcount, baseRow);
    // GEMM2 (8-phase, K=2048): out = (P * Bt^T) * rowinv
    gemm8p_k<2, 1, 5><<<(chunkT / 256) * 2, 512, 0, stream>>>(
        Pbuf, Bt, (void*)(out_mu + (size_t)baseRow * FDIM), FDIM, MDIM, 1,
        nullptr, nullptr, nullptr, rowinv);
  }
  // two-level argmax refine: gather ambiguous rows, split-GEMM, decide idx
  gather_prep_k<<<QCAP / 4, 256, 0, stream>>>(queue, qcount, inputs, inv_n, Qh, Ql);
  gemm_ref_k<<<16 * (QCAP / 128), 256, 0, stream>>>(
      Qh, Ql, Bh, Bl, Sref, MDIM, FDIM, 4, qcount);
  refine2_k<<<QCAP / 4, 256, 0, stream>>>(queue, qcount, Sref, inputs, memory, idx);
  // deterministic segment-sum (no atomics), then blend
  segsum_k<<<MDIM, 256, 0, stream>>>(idx, inputs, inv_n, updates);
  final_update_k<<<(MDIM * FDIM / 4) / 256, 256, 0, stream>>>(memory, updates, out_um);
}

// Round 15
// 726.322 us; speedup vs baseline: 1.3696x; 1.3696x over previous
//
#include <hip/hip_runtime.h>
#include <stdint.h>

#define N_TOK   65536
#define MDIM    2048
#define FDIM    512
#define SCALE_F 10.0f
#define TAU_BF  1.2e-3f   // level-1: bf16-S ambiguity (~9 sigma)
#define TAU_SP  2e-5f     // level-2: split-S ambiguity (~100 sigma)
#define QCAP    8192

typedef __attribute__((ext_vector_type(8))) unsigned short u16x8;
typedef __attribute__((ext_vector_type(4))) unsigned short u16x4;
typedef __attribute__((ext_vector_type(8))) __bf16 bf16x8;
typedef __attribute__((ext_vector_type(4))) float f32x4;

__device__ __forceinline__ unsigned short f2bf(float f) {
  unsigned int u = __builtin_bit_cast(unsigned int, f);
  u += 0x7fffu + ((u >> 16) & 1u);   // round-to-nearest-even
  return (unsigned short)(u >> 16);
}
__device__ __forceinline__ float bf2f(unsigned short b) {
  return __builtin_bit_cast(float, (unsigned int)b << 16);
}
__device__ __forceinline__ f32x4 mfma16(u16x8 a, u16x8 b, f32x4 c) {
  return __builtin_amdgcn_mfma_f32_16x16x32_bf16(
      __builtin_bit_cast(bf16x8, a), __builtin_bit_cast(bf16x8, b), c, 0, 0, 0);
}
__device__ __forceinline__ void gload16(const unsigned short* g, unsigned short* l) {
  __builtin_amdgcn_global_load_lds(
      (const __attribute__((address_space(1))) unsigned int*)g,
      (__attribute__((address_space(3))) unsigned int*)l,
      16, 0, 0);
}
// order-preserving float->u32; tie -> smaller col wins (np.argmax)
__device__ __forceinline__ unsigned long long packkey(float x, int col) {
  unsigned u = __builtin_bit_cast(unsigned, x);
  u = (u & 0x80000000u) ? ~u : (u | 0x80000000u);
  return ((unsigned long long)u << 32) | (unsigned)(2048 - col);
}
__device__ __forceinline__ float unpackval(unsigned long long k) {
  unsigned u = (unsigned)(k >> 32);
  u = (u & 0x80000000u) ? (u & 0x7fffffffu) : ~u;
  return __builtin_bit_cast(float, u);
}
__device__ __forceinline__ int unpackcol(unsigned long long k) {
  return 2048 - (int)(k & 0xffffffffu);
}
__device__ __forceinline__ void merge2(unsigned long long& k1, unsigned long long& k2,
                                       unsigned long long o1, unsigned long long o2) {
  if (o1 > k1) { k2 = (k1 > o2) ? k1 : o2; k1 = o1; }
  else if (o1 > k2) { k2 = o1; }
}
// 16B-slot swizzle within one 32x128-f32 LDS tile row
__device__ __forceinline__ int sslot(int colslot, int lrow) {
  return colslot ^ (lrow & 7);
}

// ---------------- zero queue counter ----------------
__global__ __launch_bounds__(64) void zero_k(int* __restrict__ qcount) {
  if (threadIdx.x == 0) *qcount = 0;
}

// ---------------- memory_norm -> bf16 hi/lo ----------------
__global__ __launch_bounds__(64) void prep_memory_k(
    const float* __restrict__ mem, unsigned short* __restrict__ Bh,
    unsigned short* __restrict__ Bl) {
  const int m = blockIdx.x;
  const int lane = threadIdx.x;
  const float* row = mem + (size_t)m * FDIM;
  float4 a = *(const float4*)(row + lane * 4);
  float4 b = *(const float4*)(row + 256 + lane * 4);
  float s = a.x * a.x + a.y * a.y + a.z * a.z + a.w * a.w +
            b.x * b.x + b.y * b.y + b.z * b.z + b.w * b.w;
  #pragma unroll
  for (int off = 1; off < 64; off <<= 1) s += __shfl_xor(s, off);
  const float rn = 1.0f / sqrtf(fmaxf(s, 1e-12f));
  float v[8] = {a.x, a.y, a.z, a.w, b.x, b.y, b.z, b.w};
  #pragma unroll
  for (int h = 0; h < 2; ++h) {
    ushort4 hs, lo;
    #pragma unroll
    for (int q = 0; q < 4; ++q) {
      float x = v[h * 4 + q] * rn;
      unsigned short hb = f2bf(x);
      ((unsigned short*)&hs)[q] = hb;
      ((unsigned short*)&lo)[q] = f2bf(x - bf2f(hb));
    }
    const size_t e = (size_t)m * FDIM + h * 256 + lane * 4;
    *(ushort4*)(Bh + e) = hs;
    *(ushort4*)(Bl + e) = lo;
  }
}

// ---------------- transpose Bh [M][F] -> Bt [F][M] ----------------
__global__ __launch_bounds__(256) void transpose_k(
    const unsigned short* __restrict__ Bh, unsigned short* __restrict__ Bt) {
  __shared__ unsigned short t[32][33];
  const int m0 = blockIdx.x * 32, f0 = blockIdx.y * 32;
  const int tx = threadIdx.x & 31, ty = threadIdx.x >> 5;
  #pragma unroll
  for (int r = ty; r < 32; r += 8)
    t[r][tx] = Bh[(size_t)(m0 + r) * FDIM + f0 + tx];
  __syncthreads();
  #pragma unroll
  for (int r = ty; r < 32; r += 8)
    Bt[(size_t)(f0 + r) * MDIM + m0 + tx] = t[tx][r];
}

// ------- fused: input row inv-norm + inputs_norm -> bf16 (one pass) -------
__global__ __launch_bounds__(256) void prep_a_k(
    const float* __restrict__ inp, float* __restrict__ inv_n,
    unsigned short* __restrict__ Ah, int baseRow) {
  const int r = blockIdx.x * 4 + (threadIdx.x >> 6);   // chunk-local row
  const int lane = threadIdx.x & 63;
  const int grow = baseRow + r;
  const float* x = inp + (size_t)grow * FDIM;
  float4 a = *(const float4*)(x + lane * 4);
  float4 b = *(const float4*)(x + 256 + lane * 4);
  float s = a.x * a.x + a.y * a.y + a.z * a.z + a.w * a.w +
            b.x * b.x + b.y * b.y + b.z * b.z + b.w * b.w;
  #pragma unroll
  for (int off = 1; off < 64; off <<= 1) s += __shfl_xor(s, off);
  const float rn = 1.0f / sqrtf(fmaxf(s, 1e-12f));
  if (lane == 0) inv_n[grow] = rn;
  ushort4 h0, h1;
  h0.x = f2bf(a.x * rn); h0.y = f2bf(a.y * rn);
  h0.z = f2bf(a.z * rn); h0.w = f2bf(a.w * rn);
  h1.x = f2bf(b.x * rn); h1.y = f2bf(b.y * rn);
  h1.z = f2bf(b.z * rn); h1.w = f2bf(b.w * rn);
  *(ushort4*)(Ah + (size_t)r * FDIM + lane * 4) = h0;
  *(ushort4*)(Ah + (size_t)r * FDIM + 256 + lane * 4) = h1;
}

// ------------- GEMM (r12-proven): C = A * B^T, 128x128 tile, dbuf LDS -------------
// MODE 1: P=bf16(exp(10*s)) + sidecar per (row,bx) via 4-phase 16KB LDS-scratch
// epilogue (aliases buf0).  MODE 0 + SPLIT: hi/lo bf16 compensation, fp32 C.
template <int MODE, bool SPLIT, bool SWZ>
__global__ __launch_bounds__(256) void gemm_bt_k(
    const unsigned short* __restrict__ Ah, const unsigned short* __restrict__ Al,
    const unsigned short* __restrict__ Bh, const unsigned short* __restrict__ Bl,
    void* __restrict__ Cv, int N, int K, int nbxLog2,
    const int* __restrict__ qlimit, float* __restrict__ ssum,
    unsigned long long* __restrict__ sk1, unsigned long long* __restrict__ sk2) {
  int wg = blockIdx.x;
  if (SWZ) {  // bijective: nwg % 8 == 0 guaranteed by launcher
    const int q = gridDim.x >> 3;
    wg = (wg & 7) * q + (wg >> 3);
  }
  const int bx = wg & ((1 << nbxLog2) - 1);
  const int by = wg >> nbxLog2;
  const int m0 = by * 128, n0 = bx * 128;
  if (qlimit) {
    int lim = *qlimit; if (lim > QCAP) lim = QCAP;
    lim = (lim + 127) & ~127;
    if (m0 >= lim) return;
  }
  constexpr int BUF_B = (SPLIT ? 4 : 2) * 8192;       // bytes per staging buffer
  __shared__ alignas(16) char smem[2 * BUF_B];

  const int tid = threadIdx.x;
  const int lane = tid & 63, wave = tid >> 6;
  const int wr = wave >> 1, wc = wave & 1;
  const int lr = lane & 15, ls = lane >> 4;

  f32x4 acc[4][4] = {};

  const int row0 = wave * 32 + (lane >> 2);
  const int row1 = row0 + 16;
  const int ce = (lane & 3) * 8;
  const unsigned short* gA0 = Ah + (size_t)(m0 + row0) * K + ce;
  const unsigned short* gA1 = Ah + (size_t)(m0 + row1) * K + ce;
  const unsigned short* gB0 = Bh + (size_t)(n0 + row0) * K + ce;
  const unsigned short* gB1 = Bh + (size_t)(n0 + row1) * K + ce;
  const unsigned short* gAl0 = nullptr; const unsigned short* gAl1 = nullptr;
  const unsigned short* gBl0 = nullptr; const unsigned short* gBl1 = nullptr;
  if constexpr (SPLIT) {
    gAl0 = Al + (size_t)(m0 + row0) * K + ce;
    gAl1 = Al + (size_t)(m0 + row1) * K + ce;
    gBl0 = Bl + (size_t)(n0 + row0) * K + ce;
    gBl1 = Bl + (size_t)(n0 + row1) * K + ce;
  }

  auto stage = [&](int buf) {
    char* sb = smem + buf * BUF_B;
    unsigned short* bAh = (unsigned short*)sb;
    unsigned short* bBh = (unsigned short*)(sb + 8192);
    gload16(gA0, &bAh[wave * 1024]); gload16(gA1, &bAh[wave * 1024 + 512]);
    gload16(gB0, &bBh[wave * 1024]); gload16(gB1, &bBh[wave * 1024 + 512]);
    if constexpr (SPLIT) {
      unsigned short* bAl = (unsigned short*)(sb + 16384);
      unsigned short* bBl = (unsigned short*)(sb + 24576);
      gload16(gAl0, &bAl[wave * 1024]); gload16(gAl1, &bAl[wave * 1024 + 512]);
      gload16(gBl0, &bBl[wave * 1024]); gload16(gBl1, &bBl[wave * 1024 + 512]);
    }
    gA0 += 32; gA1 += 32; gB0 += 32; gB1 += 32;
    if constexpr (SPLIT) { gAl0 += 32; gAl1 += 32; gBl0 += 32; gBl1 += 32; }
  };

  const int nk = K >> 5;
  stage(0);
  __syncthreads();
  for (int ks = 0; ks < nk; ++ks) {
    const int cur = ks & 1;
    if (ks + 1 < nk) stage(cur ^ 1);
    const char* sb = smem + cur * BUF_B;
    const unsigned short* cAh = (const unsigned short*)sb;
    const unsigned short* cBh = (const unsigned short*)(sb + 8192);
    u16x8 fa[4], fb[4], fal[4], fbl[4];
    #pragma unroll
    for (int i = 0; i < 4; ++i) {
      const int ra = (wr * 64 + i * 16 + lr) * 32 + ls * 8;
      const int rb = (wc * 64 + i * 16 + lr) * 32 + ls * 8;
      fa[i] = *(const u16x8*)&cAh[ra];
      fb[i] = *(const u16x8*)&cBh[rb];
      if constexpr (SPLIT) {
        fal[i] = *(const u16x8*)&((const unsigned short*)(sb + 16384))[ra];
        fbl[i] = *(const u16x8*)&((const unsigned short*)(sb + 24576))[rb];
      }
    }
    #pragma unroll
    for (int i = 0; i < 4; ++i)
      #pragma unroll
      for (int j = 0; j < 4; ++j) {
        acc[i][j] = mfma16(fa[i], fb[j], acc[i][j]);
        if constexpr (SPLIT) {
          acc[i][j] = mfma16(fal[i], fb[j], acc[i][j]);
          acc[i][j] = mfma16(fa[i], fbl[j], acc[i][j]);
        }
      }
    __syncthreads();
  }

  if constexpr (MODE == 1) {
    unsigned short* P = (unsigned short*)Cv;
    float* sS = (float*)smem;          // 32 rows x 128 f32 (swizzled 16B slots)
    #pragma unroll
    for (int ph = 0; ph < 4; ++ph) {
      __syncthreads();
      if (wr == (ph >> 1)) {           // 2 waves dump rows [ph*32, ph*32+32)
        const int ibase = (ph & 1) * 2;
        #pragma unroll
        for (int di = 0; di < 2; ++di)
          #pragma unroll
          for (int q = 0; q < 4; ++q) {
            const int lrow = di * 16 + ls * 4 + q;
            float* sr = &sS[lrow * 128];
            #pragma unroll
            for (int j = 0; j < 4; ++j) {
              const int col = wc * 64 + j * 16 + lr;
              sr[sslot(col >> 2, lrow) * 4 + (col & 3)] = acc[ibase + di][j][q];
            }
          }
      }
      __syncthreads();
      const int lrow = tid >> 3;
      const int h = tid & 7;
      const int grow = m0 + ph * 32 + lrow;
      const float* sr = &sS[lrow * 128];
      float esum = 0.f, m1v = -3.4e38f, m2v = -3.4e38f;
      int c1 = 2047;
      #pragma unroll
      for (int k = 0; k < 4; ++k) {
        const int lslot = k * 8 + h;
        const f32x4 v4 = *(const f32x4*)&sr[sslot(lslot, lrow) * 4];
        unsigned short pk4[4];
        #pragma unroll
        for (int e = 0; e < 4; ++e) {
          const float s = v4[e];
          const int col = n0 + lslot * 4 + e;
          if (s > m1v) { m2v = m1v; m1v = s; c1 = col; }
          else if (s > m2v) { m2v = s; }
          const float ex = __expf(SCALE_F * s);
          esum += ex;
          pk4[e] = f2bf(ex);
        }
        *(u16x4*)&P[(size_t)grow * N + n0 + lslot * 4] = *(u16x4*)pk4;
      }
      unsigned long long k1 = packkey(m1v, c1);
      unsigned long long k2 = packkey(m2v, 2047);
      #pragma unroll
      for (int off = 1; off < 8; off <<= 1) {
        const unsigned long long o1 = __shfl_xor(k1, off);
        const unsigned long long o2 = __shfl_xor(k2, off);
        esum += __shfl_xor(esum, off);
        merge2(k1, k2, o1, o2);
      }
      if (h == 0) {
        const size_t sp = (size_t)grow * 16 + bx;
        ssum[sp] = esum; sk1[sp] = k1; sk2[sp] = k2;
      }
    }
  } else {
    float* C = (float*)Cv;
    #pragma unroll
    for (int i = 0; i < 4; ++i) {
      const int rrow = m0 + wr * 64 + i * 16 + ls * 4;
      #pragma unroll
      for (int j = 0; j < 4; ++j) {
        const int col = n0 + wc * 64 + j * 16 + lr;
        #pragma unroll
        for (int q = 0; q < 4; ++q)
          C[(size_t)(rrow + q) * N + col] = acc[i][j][q];
      }
    }
  }
}

// ====== GEMM2 (r13-proven): 8-phase 256x256, K=2048, C = (A*B^T)*rowinv ======
// 512 thr (8 waves 2Mx4N), BK=64, 2 K-tiles/iter, counted vmcnt(7) at phases
// 0/4, raw barrier pairs, setprio around MFMA, XOR slot-swizzled LDS.
__global__ __launch_bounds__(512) void gemm8p2_k(
    const unsigned short* __restrict__ Am, const unsigned short* __restrict__ Bm,
    float* __restrict__ C, int N, int K,
    const float* __restrict__ rowinv) {
  constexpr int NTT = 32;      // K/64 = 2048/64
  constexpr int NITER = NTT / 2;
  __shared__ alignas(16) char smem[131072];
  int wg = blockIdx.x;
  { const int q = gridDim.x >> 3; wg = (wg & 7) * q + (wg >> 3); }  // XCD swizzle
  const int bx0 = wg & 1;
  const int by = wg >> 1;
  const int m0 = by * 256;
  const int tid = threadIdx.x;
  const int lane = tid & 63, wid = tid >> 6;
  const int wm = wid >> 2, wn = wid & 3;
  const int lr = lane & 15, ls = lane >> 4;
  const int c16 = (lane & 7) ^ (lane >> 3);
  const int lrow8 = lane >> 3;

  f32x4 acc[8][4] = {};
  u16x8 bF[4][2];

  auto stageB = [&](int T, int half) {
    const int ko = T * 64;
    char* dst0 = smem + (T & 1) * 65536 + 32768 + half * 16384;
    #pragma unroll
    for (int c = 0; c < 2; ++c) {
      const int R = (wid * 2 + c) * 8;
      const int rg = bx0 * 256 + half * 128 + R + lrow8;
      gload16(Bm + (size_t)rg * K + ko + c16 * 8,
              (unsigned short*)(dst0 + R * 128));
    }
  };
  auto stageA = [&](int T, int q) {
    const int ko = T * 64;
    const int half = wid >> 2;
    const int R = q * 32 + (wid & 3) * 8;
    char* dst = smem + (T & 1) * 65536 + half * 16384 + R * 128;
    const int rg = m0 + half * 128 + R + lrow8;
    gload16(Am + (size_t)rg * K + ko + c16 * 8, (unsigned short*)dst);
  };
  auto ldsA = [&](int b, int rl, int ks) -> u16x8 {
    const int p = (ks * 4 + ls) ^ (rl & 7);
    return *(const u16x8*)(smem + b * 65536 + wm * 16384 + rl * 128 + p * 16);
  };
  auto ldsB = [&](int b, int rlb, int ks) -> u16x8 {
    const int half = rlb >> 7, rl = rlb & 127;
    const int p = (ks * 4 + ls) ^ (rl & 7);
    return *(const u16x8*)(smem + b * 65536 + 32768 + half * 16384 + rl * 128 + p * 16);
  };

  stageB(0, 0); stageB(0, 1);
  stageA(0, 0); stageA(0, 1); stageA(0, 2); stageA(0, 3);
  stageB(1, 0); stageB(1, 1);
  stageA(1, 0); stageA(1, 1); stageA(1, 2);

  for (int it = 0; it < NITER; ++it) {
    const int T0 = 2 * it, T1 = T0 + 1;
    #pragma unroll
    for (int ph = 0; ph < 8; ++ph) {
      const int tb = (ph < 4) ? 0 : 1;
      const int ql = ph & 3;
      if (ql == 0) {
        if (ph == 4 && it == NITER - 1)
          asm volatile("s_waitcnt vmcnt(0)" ::: "memory");
        else
          asm volatile("s_waitcnt vmcnt(7)" ::: "memory");
        __builtin_amdgcn_sched_barrier(0);
        __builtin_amdgcn_s_barrier();
        #pragma unroll
        for (int nj = 0; nj < 4; ++nj)
          #pragma unroll
          for (int ks = 0; ks < 2; ++ks)
            bF[nj][ks] = ldsB(tb, wn * 64 + nj * 16 + lr, ks);
      } else {
        __builtin_amdgcn_s_barrier();
      }
      u16x8 aF[2][2];
      #pragma unroll
      for (int di = 0; di < 2; ++di)
        #pragma unroll
        for (int ks = 0; ks < 2; ++ks)
          aF[di][ks] = ldsA(tb, ql * 32 + di * 16 + lr, ks);
      if (ph == 0) { if (T1 < NTT) stageA(T1, 3); }
      if (ph == 1) { if (T0 + 2 < NTT) stageB(T0 + 2, 0); }
      if (ph == 2) { if (T0 + 2 < NTT) { stageB(T0 + 2, 1); stageA(T0 + 2, 0); } }
      if (ph == 3) { if (T0 + 2 < NTT) { stageA(T0 + 2, 1); stageA(T0 + 2, 2); } }
      if (ph == 4) { if (T0 + 2 < NTT) stageA(T0 + 2, 3); }
      if (ph == 5) { if (T1 + 2 < NTT) stageB(T1 + 2, 0); }
      if (ph == 6) { if (T1 + 2 < NTT) { stageB(T1 + 2, 1); stageA(T1 + 2, 0); } }
      if (ph == 7) { if (T1 + 2 < NTT) { stageA(T1 + 2, 1); stageA(T1 + 2, 2); } }
      __builtin_amdgcn_s_setprio(1);
      #pragma unroll
      for (int di = 0; di < 2; ++di)
        #pragma unroll
        for (int nj = 0; nj < 4; ++nj)
          #pragma unroll
          for (int ks = 0; ks < 2; ++ks)
            acc[ql * 2 + di][nj] = mfma16(aF[di][ks], bF[nj][ks], acc[ql * 2 + di][nj]);
      __builtin_amdgcn_s_setprio(0);
      __builtin_amdgcn_s_barrier();
    }
  }

  const int n0 = bx0 * 256;
  #pragma unroll
  for (int mi = 0; mi < 8; ++mi) {
    const int rbase = m0 + wm * 128 + mi * 16 + ls * 4;
    #pragma unroll
    for (int q = 0; q < 4; ++q) {
      const float ri = rowinv[rbase + q];
      #pragma unroll
      for (int nj = 0; nj < 4; ++nj) {
        const int col = n0 + wn * 64 + nj * 16 + lr;
        C[(size_t)(rbase + q) * N + col] = acc[mi][nj][q] * ri;
      }
    }
  }
}

// ------- merge 16 sidecar partials per row: idx, rowinv, queue -------
__global__ __launch_bounds__(256) void rowstat_k(
    const float* __restrict__ ssum, const unsigned long long* __restrict__ sk1,
    const unsigned long long* __restrict__ sk2, int* __restrict__ idx,
    float* __restrict__ rowinv, int* __restrict__ queue,
    int* __restrict__ qcount, int baseRow) {
  const int row = blockIdx.x * 16 + (threadIdx.x >> 4);
  const int p = threadIdx.x & 15;
  const size_t sp = (size_t)row * 16 + p;
  float sum = ssum[sp];
  unsigned long long k1 = sk1[sp], k2 = sk2[sp];
  #pragma unroll
  for (int off = 1; off < 16; off <<= 1) {
    const unsigned long long o1 = __shfl_xor(k1, off);
    const unsigned long long o2 = __shfl_xor(k2, off);
    sum += __shfl_xor(sum, off);
    merge2(k1, k2, o1, o2);
  }
  if (p == 0) {
    const int tok = baseRow + row;
    idx[tok] = unpackcol(k1);
    rowinv[row] = 1.0f / sum;
    if (unpackval(k1) - unpackval(k2) < TAU_BF) {
      int slot = atomicAdd(qcount, 1);
      if (slot < QCAP) queue[slot] = tok;
    }
  }
}

// ------- gather queued tokens' normalized rows -> compact hi/lo matrix -------
__global__ __launch_bounds__(256) void gather_prep_k(
    const int* __restrict__ queue, const int* __restrict__ qcount,
    const float* __restrict__ inp, const float* __restrict__ inv_n,
    unsigned short* __restrict__ Qh, unsigned short* __restrict__ Ql) {
  const int w = blockIdx.x * 4 + (threadIdx.x >> 6);
  const int lane = threadIdx.x & 63;
  int cnt = *qcount; if (cnt > QCAP) cnt = QCAP;
  if (w >= cnt) return;
  const int tok = queue[w];
  const float rn = inv_n[tok];
  const float* x = inp + (size_t)tok * FDIM;
  #pragma unroll
  for (int h = 0; h < 2; ++h) {
    float4 xv = *(const float4*)(x + h * 256 + lane * 4);
    float vv[4] = {xv.x, xv.y, xv.z, xv.w};
    ushort4 hs, lo;
    #pragma unroll
    for (int q = 0; q < 4; ++q) {
      float v = vv[q] * rn;
      unsigned short hb = f2bf(v);
      ((unsigned short*)&hs)[q] = hb;
      ((unsigned short*)&lo)[q] = f2bf(v - bf2f(hb));
    }
    const size_t e = (size_t)w * FDIM + h * 256 + lane * 4;
    *(ushort4*)(Qh + e) = hs;
    *(ushort4*)(Ql + e) = lo;
  }
}

// ------- level-2: full-row top-2 on split-S; fp64 pair-decide; write idx -------
__global__ __launch_bounds__(256) void refine2_k(
    const int* __restrict__ queue, const int* __restrict__ qcount,
    const float* __restrict__ Sref, const float* __restrict__ inp,
    const float* __restrict__ mem, int* __restrict__ idx) {
  const int w = blockIdx.x * 4 + (threadIdx.x >> 6);
  const int lane = threadIdx.x & 63;
  int cnt = *qcount; if (cnt > QCAP) cnt = QCAP;
  if (w >= cnt) return;
  const int tok = queue[w];
  const float* srow = Sref + (size_t)w * MDIM;
  float m1 = -3.4e38f, m2 = -3.4e38f;
  int i1 = 0x7fffffff, i2 = 0x7fffffff;
  #pragma unroll
  for (int i = 0; i < 8; ++i) {
    const float4 vv = *(const float4*)(srow + i * 256 + lane * 4);
    const float xs[4] = {vv.x, vv.y, vv.z, vv.w};
    #pragma unroll
    for (int q = 0; q < 4; ++q) {
      const float x = xs[q];
      const int ii = i * 256 + lane * 4 + q;
      if (x > m1 || (x == m1 && ii < i1)) { m2 = m1; i2 = i1; m1 = x; i1 = ii; }
      else if (x > m2 || (x == m2 && ii < i2)) { m2 = x; i2 = ii; }
    }
  }
  #pragma unroll
  for (int off = 1; off < 64; off <<= 1) {
    const float n1 = __shfl_xor(m1, off), n2 = __shfl_xor(m2, off);
    const int j1 = __shfl_xor(i1, off), j2 = __shfl_xor(i2, off);
    if (n1 > m1 || (n1 == m1 && j1 < i1)) {
      if (m1 > n2 || (m1 == n2 && i1 < j2)) { m2 = m1; i2 = i1; }
      else { m2 = n2; i2 = j2; }
      m1 = n1; i1 = j1;
    } else if (n1 > m2 || (n1 == m2 && j1 < i2)) { m2 = n1; i2 = j1; }
  }
  int pick = i1;
  if (m1 - m2 < TAU_SP) {
    const int a = (i1 < i2) ? i1 : i2, b = (i1 < i2) ? i2 : i1;
    const float* x = inp + (size_t)tok * FDIM;
    const float* ma = mem + (size_t)a * FDIM;
    const float* mb = mem + (size_t)b * FDIM;
    double da = 0, db = 0, na = 0, nb = 0;
    #pragma unroll
    for (int j = 0; j < 8; ++j) {
      const int e = lane * 8 + j;
      const double xv = x[e], av = ma[e], bv = mb[e];
      da += xv * av; na += av * av;
      db += xv * bv; nb += bv * bv;
    }
    #pragma unroll
    for (int off = 1; off < 64; off <<= 1) {
      da += __shfl_xor(da, off); na += __shfl_xor(na, off);
      db += __shfl_xor(db, off); nb += __shfl_xor(nb, off);
    }
    const double d1 = da / sqrt(fmax(na, 1e-12));
    const double d2 = db / sqrt(fmax(nb, 1e-12));
    if (d2 > d1) pick = b;
    else pick = a;
  }
  if (lane == 0) idx[tok] = pick;
}

// ------- deterministic segment-sum: one block per code, no atomics -------
__global__ __launch_bounds__(256) void segsum_k(
    const int* __restrict__ idx, const float* __restrict__ inp,
    const float* __restrict__ inv_n, float* __restrict__ updates) {
  __shared__ int lst[256];
  __shared__ int lcnt;
  const int m = blockIdx.x;
  const int t = threadIdx.x;
  float a0 = 0.f, a1 = 0.f;
  for (int base = 0; base < N_TOK; base += 4096) {
    if (t == 0) lcnt = 0;
    __syncthreads();
    #pragma unroll
    for (int u = 0; u < 4; ++u) {
      const int off4 = (u * 256 + t) * 4;
      const int4 v = *(const int4*)&idx[base + off4];
      if (v.x == m) { int p = atomicAdd(&lcnt, 1); if (p < 256) lst[p] = base + off4 + 0; }
      if (v.y == m) { int p = atomicAdd(&lcnt, 1); if (p < 256) lst[p] = base + off4 + 1; }
      if (v.z == m) { int p = atomicAdd(&lcnt, 1); if (p < 256) lst[p] = base + off4 + 2; }
      if (v.w == m) { int p = atomicAdd(&lcnt, 1); if (p < 256) lst[p] = base + off4 + 3; }
    }
    __syncthreads();
    int c = lcnt; if (c > 256) c = 256;
    if (t == 0 && c > 1) {
      for (int i = 1; i < c; ++i) {
        int key = lst[i], j = i - 1;
        while (j >= 0 && lst[j] > key) { lst[j + 1] = lst[j]; --j; }
        lst[j + 1] = key;
      }
    }
    __syncthreads();
    for (int i = 0; i < c; ++i) {
      const int tok = lst[i];
      const float rn = inv_n[tok];
      const float2 xv = *(const float2*)&inp[(size_t)tok * FDIM + t * 2];
      a0 += xv.x * rn; a1 += xv.y * rn;
    }
    __syncthreads();
  }
  *(float2*)&updates[(size_t)m * FDIM + t * 2] = make_float2(a0, a1);
}

// ---------------- final blend (fp32 out) ----------------
__global__ __launch_bounds__(256) void final_update_k(
    const float* __restrict__ mem, const float* __restrict__ upd,
    float* __restrict__ out) {
  const size_t i = ((size_t)blockIdx.x * 256 + threadIdx.x) * 4;
  float4 m = *(const float4*)(mem + i);
  float4 u = *(const float4*)(upd + i);
  float4 r;
  r.x = m.x * 0.9f + u.x * 0.1f;
  r.y = m.y * 0.9f + u.y * 0.1f;
  r.z = m.z * 0.9f + u.z * 0.1f;
  r.w = m.w * 0.9f + u.w * 0.1f;
  *(float4*)(out + i) = r;
}

extern "C" void kernel_launch(void* const* d_in, const int* in_sizes, int n_in,
                              void* d_out, int out_size, void* d_ws, size_t ws_size,
                              hipStream_t stream) {
  const float* inputs = (const float*)d_in[0];
  const float* memory = (const float*)d_in[1];
  if (n_in >= 2 && in_sizes[0] != N_TOK * FDIM) {  // order guard
    inputs = (const float*)d_in[1];
    memory = (const float*)d_in[0];
  }
  float* out_mu = (float*)d_out;                       // [N][F] fp32
  float* out_um = out_mu + (size_t)N_TOK * FDIM;       // [M][F] fp32

  char* base = (char*)d_ws;
  size_t off = 0;
  auto take = [&](size_t bytes) -> char* {
    char* p = base + off;
    off = (off + bytes + 255) & ~(size_t)255;
    return p;
  };
  unsigned short* Bh = (unsigned short*)take((size_t)MDIM * FDIM * 2);
  unsigned short* Bl = (unsigned short*)take((size_t)MDIM * FDIM * 2);
  unsigned short* Bt = (unsigned short*)take((size_t)MDIM * FDIM * 2);
  float* inv_n = (float*)take((size_t)N_TOK * 4);
  float* updates = (float*)take((size_t)MDIM * FDIM * 4);
  int* idx = (int*)take((size_t)N_TOK * 4);
  int* queue = (int*)take((size_t)QCAP * 4);
  int* qcount = (int*)take(256);
  unsigned short* Qh = (unsigned short*)take((size_t)QCAP * FDIM * 2);
  unsigned short* Ql = (unsigned short*)take((size_t)QCAP * FDIM * 2);
  float* Sref = (float*)take((size_t)QCAP * MDIM * 4);
  const size_t fixed = off;

  // per-token: Ah 1024 + P 4096 + sidecar 16*(4+8+8)=320 + rowinv 4
  int chunkT = 65536;  // single pass if ws allows
  while (chunkT > 2048 && fixed + (size_t)chunkT * 5700 + 8192 > ws_size)
    chunkT >>= 1;
  if (fixed + (size_t)chunkT * 5700 + 8192 > ws_size) return;  // ws too small

  unsigned short* Ah = (unsigned short*)take((size_t)chunkT * FDIM * 2);
  unsigned short* Pbuf = (unsigned short*)take((size_t)chunkT * MDIM * 2);
  float* ssum = (float*)take((size_t)chunkT * 16 * 4);
  unsigned long long* sk1 = (unsigned long long*)take((size_t)chunkT * 16 * 8);
  unsigned long long* sk2 = (unsigned long long*)take((size_t)chunkT * 16 * 8);
  float* rowinv = (float*)take((size_t)chunkT * 4);

  zero_k<<<1, 64, 0, stream>>>(qcount);
  prep_memory_k<<<MDIM, 64, 0, stream>>>(memory, Bh, Bl);
  transpose_k<<<dim3(MDIM / 32, FDIM / 32), 256, 0, stream>>>(Bh, Bt);

  const int nby = chunkT / 128;
  for (int baseRow = 0; baseRow < N_TOK; baseRow += chunkT) {
    prep_a_k<<<chunkT / 4, 256, 0, stream>>>(inputs, inv_n, Ah, baseRow);
    // GEMM1 (r12 128^2 dbuf + fused exp/sidecar epilogue)
    gemm_bt_k<1, false, true><<<16 * nby, 256, 0, stream>>>(
        Ah, nullptr, Bh, nullptr, (void*)Pbuf, MDIM, FDIM, 4, nullptr,
        ssum, sk1, sk2);
    rowstat_k<<<chunkT / 16, 256, 0, stream>>>(
        ssum, sk1, sk2, idx, rowinv, queue, qcount, baseRow);
    // GEMM2 (r13 8-phase 256^2, K=2048): out = (P * Bt^T) * rowinv
    gemm8p2_k<<<(chunkT / 256) * 2, 512, 0, stream>>>(
        Pbuf, Bt, out_mu + (size_t)baseRow * FDIM, FDIM, MDIM, rowinv);
  }
  // two-level argmax refine: gather ambiguous rows, split-GEMM, decide idx
  gather_prep_k<<<QCAP / 4, 256, 0, stream>>>(queue, qcount, inputs, inv_n, Qh, Ql);
  gemm_bt_k<0, true, false><<<16 * (QCAP / 128), 256, 0, stream>>>(
      Qh, Ql, Bh, Bl, (void*)Sref, MDIM, FDIM, 4, qcount,
      nullptr, nullptr, nullptr);
  refine2_k<<<QCAP / 4, 256, 0, stream>>>(queue, qcount, Sref, inputs, memory, idx);
  // deterministic segment-sum (no atomics), then blend
  segsum_k<<<MDIM, 256, 0, stream>>>(idx, inputs, inv_n, updates);
  final_update_k<<<(MDIM * FDIM / 4) / 256, 256, 0, stream>>>(memory, updates, out_um);
}

// Round 16
// 652.361 us; speedup vs baseline: 1.5249x; 1.1134x over previous
//
#include <hip/hip_runtime.h>
#include <stdint.h>

#define N_TOK   65536
#define MDIM    2048
#define FDIM    512
#define SCALE_F 10.0f
#define TAU_BF  3e-4f     // level-1: fp16-S ambiguity (~17 sigma)
#define TAU_SP  2e-5f     // level-2: split-S ambiguity (>>100 sigma)
#define QCAP    8192

typedef __attribute__((ext_vector_type(8))) unsigned short u16x8;
typedef __attribute__((ext_vector_type(4))) unsigned short u16x4;
typedef __attribute__((ext_vector_type(8))) _Float16 f16x8;
typedef __attribute__((ext_vector_type(4))) float f32x4;

__device__ __forceinline__ unsigned short f2h(float f) {
  return __builtin_bit_cast(unsigned short, (_Float16)f);   // RNE
}
__device__ __forceinline__ float h2f(unsigned short u) {
  return (float)__builtin_bit_cast(_Float16, u);
}
__device__ __forceinline__ f32x4 mfma16(u16x8 a, u16x8 b, f32x4 c) {
  return __builtin_amdgcn_mfma_f32_16x16x32_f16(
      __builtin_bit_cast(f16x8, a), __builtin_bit_cast(f16x8, b), c, 0, 0, 0);
}
__device__ __forceinline__ void gload16(const unsigned short* g, unsigned short* l) {
  __builtin_amdgcn_global_load_lds(
      (const __attribute__((address_space(1))) unsigned int*)g,
      (__attribute__((address_space(3))) unsigned int*)l,
      16, 0, 0);
}
// order-preserving float->u32; tie -> smaller col wins (np.argmax)
__device__ __forceinline__ unsigned long long packkey(float x, int col) {
  unsigned u = __builtin_bit_cast(unsigned, x);
  u = (u & 0x80000000u) ? ~u : (u | 0x80000000u);
  return ((unsigned long long)u << 32) | (unsigned)(2048 - col);
}
__device__ __forceinline__ float unpackval(unsigned long long k) {
  unsigned u = (unsigned)(k >> 32);
  u = (u & 0x80000000u) ? (u & 0x7fffffffu) : ~u;
  return __builtin_bit_cast(float, u);
}
__device__ __forceinline__ int unpackcol(unsigned long long k) {
  return 2048 - (int)(k & 0xffffffffu);
}
__device__ __forceinline__ void merge2(unsigned long long& k1, unsigned long long& k2,
                                       unsigned long long o1, unsigned long long o2) {
  if (o1 > k1) { k2 = (k1 > o2) ? k1 : o2; k1 = o1; }
  else if (o1 > k2) { k2 = o1; }
}
// 16B-slot swizzle within one 32x128-f32 LDS tile row
__device__ __forceinline__ int sslot(int colslot, int lrow) {
  return colslot ^ (lrow & 7);
}

// ---------------- memory_norm -> fp16 hi/lo (+ zero qcount) ----------------
__global__ __launch_bounds__(64) void prep_memory_k(
    const float* __restrict__ mem, unsigned short* __restrict__ Bh,
    unsigned short* __restrict__ Bl, int* __restrict__ qcount) {
  const int m = blockIdx.x;
  const int lane = threadIdx.x;
  if (m == 0 && lane == 0) *qcount = 0;
  const float* row = mem + (size_t)m * FDIM;
  float4 a = *(const float4*)(row + lane * 4);
  float4 b = *(const float4*)(row + 256 + lane * 4);
  float s = a.x * a.x + a.y * a.y + a.z * a.z + a.w * a.w +
            b.x * b.x + b.y * b.y + b.z * b.z + b.w * b.w;
  #pragma unroll
  for (int off = 1; off < 64; off <<= 1) s += __shfl_xor(s, off);
  const float rn = 1.0f / sqrtf(fmaxf(s, 1e-12f));
  float v[8] = {a.x, a.y, a.z, a.w, b.x, b.y, b.z, b.w};
  #pragma unroll
  for (int h = 0; h < 2; ++h) {
    ushort4 hs, lo;
    #pragma unroll
    for (int q = 0; q < 4; ++q) {
      float x = v[h * 4 + q] * rn;
      unsigned short hb = f2h(x);
      ((unsigned short*)&hs)[q] = hb;
      ((unsigned short*)&lo)[q] = f2h(x - h2f(hb));
    }
    const size_t e = (size_t)m * FDIM + h * 256 + lane * 4;
    *(ushort4*)(Bh + e) = hs;
    *(ushort4*)(Bl + e) = lo;
  }
}

// ---------------- transpose Bh [M][F] -> Bt [F][M] ----------------
__global__ __launch_bounds__(256) void transpose_k(
    const unsigned short* __restrict__ Bh, unsigned short* __restrict__ Bt) {
  __shared__ unsigned short t[32][33];
  const int m0 = blockIdx.x * 32, f0 = blockIdx.y * 32;
  const int tx = threadIdx.x & 31, ty = threadIdx.x >> 5;
  #pragma unroll
  for (int r = ty; r < 32; r += 8)
    t[r][tx] = Bh[(size_t)(m0 + r) * FDIM + f0 + tx];
  __syncthreads();
  #pragma unroll
  for (int r = ty; r < 32; r += 8)
    Bt[(size_t)(f0 + r) * MDIM + m0 + tx] = t[tx][r];
}

// ------- fused: input row inv-norm + inputs_norm -> fp16 (one pass) -------
__global__ __launch_bounds__(256) void prep_a_k(
    const float* __restrict__ inp, float* __restrict__ inv_n,
    unsigned short* __restrict__ Ah, int baseRow) {
  const int r = blockIdx.x * 4 + (threadIdx.x >> 6);   // chunk-local row
  const int lane = threadIdx.x & 63;
  const int grow = baseRow + r;
  const float* x = inp + (size_t)grow * FDIM;
  float4 a = *(const float4*)(x + lane * 4);
  float4 b = *(const float4*)(x + 256 + lane * 4);
  float s = a.x * a.x + a.y * a.y + a.z * a.z + a.w * a.w +
            b.x * b.x + b.y * b.y + b.z * b.z + b.w * b.w;
  #pragma unroll
  for (int off = 1; off < 64; off <<= 1) s += __shfl_xor(s, off);
  const float rn = 1.0f / sqrtf(fmaxf(s, 1e-12f));
  if (lane == 0) inv_n[grow] = rn;
  ushort4 h0, h1;
  h0.x = f2h(a.x * rn); h0.y = f2h(a.y * rn);
  h0.z = f2h(a.z * rn); h0.w = f2h(a.w * rn);
  h1.x = f2h(b.x * rn); h1.y = f2h(b.y * rn);
  h1.z = f2h(b.z * rn); h1.w = f2h(b.w * rn);
  *(ushort4*)(Ah + (size_t)r * FDIM + lane * 4) = h0;
  *(ushort4*)(Ah + (size_t)r * FDIM + 256 + lane * 4) = h1;
}

// ------------- GEMM (r12-proven): C = A * B^T, 128x128 tile, dbuf LDS -------------
// MODE 1: P=fp16(exp(10*s)) + sidecar per (row,bx) via 4-phase 16KB LDS-scratch
// epilogue (aliases buf0).  MODE 0 + SPLIT: hi/lo fp16 compensation, fp32 C.
template <int MODE, bool SPLIT, bool SWZ>
__global__ __launch_bounds__(256) void gemm_bt_k(
    const unsigned short* __restrict__ Ah, const unsigned short* __restrict__ Al,
    const unsigned short* __restrict__ Bh, const unsigned short* __restrict__ Bl,
    void* __restrict__ Cv, int N, int K, int nbxLog2,
    const int* __restrict__ qlimit, float* __restrict__ ssum,
    unsigned long long* __restrict__ sk1, unsigned long long* __restrict__ sk2) {
  int wg = blockIdx.x;
  if (SWZ) {  // bijective: nwg % 8 == 0 guaranteed by launcher
    const int q = gridDim.x >> 3;
    wg = (wg & 7) * q + (wg >> 3);
  }
  const int bx = wg & ((1 << nbxLog2) - 1);
  const int by = wg >> nbxLog2;
  const int m0 = by * 128, n0 = bx * 128;
  if (qlimit) {
    int lim = *qlimit; if (lim > QCAP) lim = QCAP;
    lim = (lim + 127) & ~127;
    if (m0 >= lim) return;
  }
  constexpr int BUF_B = (SPLIT ? 4 : 2) * 8192;       // bytes per staging buffer
  __shared__ alignas(16) char smem[2 * BUF_B];

  const int tid = threadIdx.x;
  const int lane = tid & 63, wave = tid >> 6;
  const int wr = wave >> 1, wc = wave & 1;
  const int lr = lane & 15, ls = lane >> 4;

  f32x4 acc[4][4] = {};

  const int row0 = wave * 32 + (lane >> 2);
  const int row1 = row0 + 16;
  const int ce = (lane & 3) * 8;
  const unsigned short* gA0 = Ah + (size_t)(m0 + row0) * K + ce;
  const unsigned short* gA1 = Ah + (size_t)(m0 + row1) * K + ce;
  const unsigned short* gB0 = Bh + (size_t)(n0 + row0) * K + ce;
  const unsigned short* gB1 = Bh + (size_t)(n0 + row1) * K + ce;
  const unsigned short* gAl0 = nullptr; const unsigned short* gAl1 = nullptr;
  const unsigned short* gBl0 = nullptr; const unsigned short* gBl1 = nullptr;
  if constexpr (SPLIT) {
    gAl0 = Al + (size_t)(m0 + row0) * K + ce;
    gAl1 = Al + (size_t)(m0 + row1) * K + ce;
    gBl0 = Bl + (size_t)(n0 + row0) * K + ce;
    gBl1 = Bl + (size_t)(n0 + row1) * K + ce;
  }

  auto stage = [&](int buf) {
    char* sb = smem + buf * BUF_B;
    unsigned short* bAh = (unsigned short*)sb;
    unsigned short* bBh = (unsigned short*)(sb + 8192);
    gload16(gA0, &bAh[wave * 1024]); gload16(gA1, &bAh[wave * 1024 + 512]);
    gload16(gB0, &bBh[wave * 1024]); gload16(gB1, &bBh[wave * 1024 + 512]);
    if constexpr (SPLIT) {
      unsigned short* bAl = (unsigned short*)(sb + 16384);
      unsigned short* bBl = (unsigned short*)(sb + 24576);
      gload16(gAl0, &bAl[wave * 1024]); gload16(gAl1, &bAl[wave * 1024 + 512]);
      gload16(gBl0, &bBl[wave * 1024]); gload16(gBl1, &bBl[wave * 1024 + 512]);
    }
    gA0 += 32; gA1 += 32; gB0 += 32; gB1 += 32;
    if constexpr (SPLIT) { gAl0 += 32; gAl1 += 32; gBl0 += 32; gBl1 += 32; }
  };

  const int nk = K >> 5;
  stage(0);
  __syncthreads();
  for (int ks = 0; ks < nk; ++ks) {
    const int cur = ks & 1;
    if (ks + 1 < nk) stage(cur ^ 1);
    const char* sb = smem + cur * BUF_B;
    const unsigned short* cAh = (const unsigned short*)sb;
    const unsigned short* cBh = (const unsigned short*)(sb + 8192);
    u16x8 fa[4], fb[4], fal[4], fbl[4];
    #pragma unroll
    for (int i = 0; i < 4; ++i) {
      const int ra = (wr * 64 + i * 16 + lr) * 32 + ls * 8;
      const int rb = (wc * 64 + i * 16 + lr) * 32 + ls * 8;
      fa[i] = *(const u16x8*)&cAh[ra];
      fb[i] = *(const u16x8*)&cBh[rb];
      if constexpr (SPLIT) {
        fal[i] = *(const u16x8*)&((const unsigned short*)(sb + 16384))[ra];
        fbl[i] = *(const u16x8*)&((const unsigned short*)(sb + 24576))[rb];
      }
    }
    #pragma unroll
    for (int i = 0; i < 4; ++i)
      #pragma unroll
      for (int j = 0; j < 4; ++j) {
        acc[i][j] = mfma16(fa[i], fb[j], acc[i][j]);
        if constexpr (SPLIT) {
          acc[i][j] = mfma16(fal[i], fb[j], acc[i][j]);
          acc[i][j] = mfma16(fa[i], fbl[j], acc[i][j]);
        }
      }
    __syncthreads();
  }

  if constexpr (MODE == 1) {
    unsigned short* P = (unsigned short*)Cv;
    float* sS = (float*)smem;          // 32 rows x 128 f32 (swizzled 16B slots)
    #pragma unroll
    for (int ph = 0; ph < 4; ++ph) {
      __syncthreads();
      if (wr == (ph >> 1)) {           // 2 waves dump rows [ph*32, ph*32+32)
        const int ibase = (ph & 1) * 2;
        #pragma unroll
        for (int di = 0; di < 2; ++di)
          #pragma unroll
          for (int q = 0; q < 4; ++q) {
            const int lrow = di * 16 + ls * 4 + q;
            float* sr = &sS[lrow * 128];
            #pragma unroll
            for (int j = 0; j < 4; ++j) {
              const int col = wc * 64 + j * 16 + lr;
              sr[sslot(col >> 2, lrow) * 4 + (col & 3)] = acc[ibase + di][j][q];
            }
          }
      }
      __syncthreads();
      const int lrow = tid >> 3;
      const int h = tid & 7;
      const int grow = m0 + ph * 32 + lrow;
      const float* sr = &sS[lrow * 128];
      float esum = 0.f, m1v = -3.4e38f, m2v = -3.4e38f;
      int c1 = 2047;
      #pragma unroll
      for (int k = 0; k < 4; ++k) {
        const int lslot = k * 8 + h;
        const f32x4 v4 = *(const f32x4*)&sr[sslot(lslot, lrow) * 4];
        unsigned short pk4[4];
        #pragma unroll
        for (int e = 0; e < 4; ++e) {
          const float s = v4[e];
          const int col = n0 + lslot * 4 + e;
          if (s > m1v) { m2v = m1v; m1v = s; c1 = col; }
          else if (s > m2v) { m2v = s; }
          const float ex = __expf(SCALE_F * s);
          esum += ex;
          pk4[e] = f2h(ex);
        }
        *(u16x4*)&P[(size_t)grow * N + n0 + lslot * 4] = *(u16x4*)pk4;
      }
      unsigned long long k1 = packkey(m1v, c1);
      unsigned long long k2 = packkey(m2v, 2047);
      #pragma unroll
      for (int off = 1; off < 8; off <<= 1) {
        const unsigned long long o1 = __shfl_xor(k1, off);
        const unsigned long long o2 = __shfl_xor(k2, off);
        esum += __shfl_xor(esum, off);
        merge2(k1, k2, o1, o2);
      }
      if (h == 0) {
        const size_t sp = (size_t)grow * 16 + bx;
        ssum[sp] = esum; sk1[sp] = k1; sk2[sp] = k2;
      }
    }
  } else {
    float* C = (float*)Cv;
    #pragma unroll
    for (int i = 0; i < 4; ++i) {
      const int rrow = m0 + wr * 64 + i * 16 + ls * 4;
      #pragma unroll
      for (int j = 0; j < 4; ++j) {
        const int col = n0 + wc * 64 + j * 16 + lr;
        #pragma unroll
        for (int q = 0; q < 4; ++q)
          C[(size_t)(rrow + q) * N + col] = acc[i][j][q];
      }
    }
  }
}

// ====== GEMM2 (r13-proven): 8-phase 256x256, K=2048, C = (A*B^T)*rowinv ======
__global__ __launch_bounds__(512) void gemm8p2_k(
    const unsigned short* __restrict__ Am, const unsigned short* __restrict__ Bm,
    float* __restrict__ C, int N, int K,
    const float* __restrict__ rowinv) {
  constexpr int NTT = 32;      // K/64 = 2048/64
  constexpr int NITER = NTT / 2;
  __shared__ alignas(16) char smem[131072];
  int wg = blockIdx.x;
  { const int q = gridDim.x >> 3; wg = (wg & 7) * q + (wg >> 3); }  // XCD swizzle
  const int bx0 = wg & 1;
  const int by = wg >> 1;
  const int m0 = by * 256;
  const int tid = threadIdx.x;
  const int lane = tid & 63, wid = tid >> 6;
  const int wm = wid >> 2, wn = wid & 3;
  const int lr = lane & 15, ls = lane >> 4;
  const int c16 = (lane & 7) ^ (lane >> 3);
  const int lrow8 = lane >> 3;

  f32x4 acc[8][4] = {};
  u16x8 bF[4][2];

  auto stageB = [&](int T, int half) {
    const int ko = T * 64;
    char* dst0 = smem + (T & 1) * 65536 + 32768 + half * 16384;
    #pragma unroll
    for (int c = 0; c < 2; ++c) {
      const int R = (wid * 2 + c) * 8;
      const int rg = bx0 * 256 + half * 128 + R + lrow8;
      gload16(Bm + (size_t)rg * K + ko + c16 * 8,
              (unsigned short*)(dst0 + R * 128));
    }
  };
  auto stageA = [&](int T, int q) {
    const int ko = T * 64;
    const int half = wid >> 2;
    const int R = q * 32 + (wid & 3) * 8;
    char* dst = smem + (T & 1) * 65536 + half * 16384 + R * 128;
    const int rg = m0 + half * 128 + R + lrow8;
    gload16(Am + (size_t)rg * K + ko + c16 * 8, (unsigned short*)dst);
  };
  auto ldsA = [&](int b, int rl, int ks) -> u16x8 {
    const int p = (ks * 4 + ls) ^ (rl & 7);
    return *(const u16x8*)(smem + b * 65536 + wm * 16384 + rl * 128 + p * 16);
  };
  auto ldsB = [&](int b, int rlb, int ks) -> u16x8 {
    const int half = rlb >> 7, rl = rlb & 127;
    const int p = (ks * 4 + ls) ^ (rl & 7);
    return *(const u16x8*)(smem + b * 65536 + 32768 + half * 16384 + rl * 128 + p * 16);
  };

  stageB(0, 0); stageB(0, 1);
  stageA(0, 0); stageA(0, 1); stageA(0, 2); stageA(0, 3);
  stageB(1, 0); stageB(1, 1);
  stageA(1, 0); stageA(1, 1); stageA(1, 2);

  for (int it = 0; it < NITER; ++it) {
    const int T0 = 2 * it, T1 = T0 + 1;
    #pragma unroll
    for (int ph = 0; ph < 8; ++ph) {
      const int tb = (ph < 4) ? 0 : 1;
      const int ql = ph & 3;
      if (ql == 0) {
        if (ph == 4 && it == NITER - 1)
          asm volatile("s_waitcnt vmcnt(0)" ::: "memory");
        else
          asm volatile("s_waitcnt vmcnt(7)" ::: "memory");
        __builtin_amdgcn_sched_barrier(0);
        __builtin_amdgcn_s_barrier();
        #pragma unroll
        for (int nj = 0; nj < 4; ++nj)
          #pragma unroll
          for (int ks = 0; ks < 2; ++ks)
            bF[nj][ks] = ldsB(tb, wn * 64 + nj * 16 + lr, ks);
      } else {
        __builtin_amdgcn_s_barrier();
      }
      u16x8 aF[2][2];
      #pragma unroll
      for (int di = 0; di < 2; ++di)
        #pragma unroll
        for (int ks = 0; ks < 2; ++ks)
          aF[di][ks] = ldsA(tb, ql * 32 + di * 16 + lr, ks);
      if (ph == 0) { if (T1 < NTT) stageA(T1, 3); }
      if (ph == 1) { if (T0 + 2 < NTT) stageB(T0 + 2, 0); }
      if (ph == 2) { if (T0 + 2 < NTT) { stageB(T0 + 2, 1); stageA(T0 + 2, 0); } }
      if (ph == 3) { if (T0 + 2 < NTT) { stageA(T0 + 2, 1); stageA(T0 + 2, 2); } }
      if (ph == 4) { if (T0 + 2 < NTT) stageA(T0 + 2, 3); }
      if (ph == 5) { if (T1 + 2 < NTT) stageB(T1 + 2, 0); }
      if (ph == 6) { if (T1 + 2 < NTT) { stageB(T1 + 2, 1); stageA(T1 + 2, 0); } }
      if (ph == 7) { if (T1 + 2 < NTT) { stageA(T1 + 2, 1); stageA(T1 + 2, 2); } }
      __builtin_amdgcn_s_setprio(1);
      #pragma unroll
      for (int di = 0; di < 2; ++di)
        #pragma unroll
        for (int nj = 0; nj < 4; ++nj)
          #pragma unroll
          for (int ks = 0; ks < 2; ++ks)
            acc[ql * 2 + di][nj] = mfma16(aF[di][ks], bF[nj][ks], acc[ql * 2 + di][nj]);
      __builtin_amdgcn_s_setprio(0);
      __builtin_amdgcn_s_barrier();
    }
  }

  const int n0 = bx0 * 256;
  #pragma unroll
  for (int mi = 0; mi < 8; ++mi) {
    const int rbase = m0 + wm * 128 + mi * 16 + ls * 4;
    #pragma unroll
    for (int q = 0; q < 4; ++q) {
      const float ri = rowinv[rbase + q];
      #pragma unroll
      for (int nj = 0; nj < 4; ++nj) {
        const int col = n0 + wn * 64 + nj * 16 + lr;
        C[(size_t)(rbase + q) * N + col] = acc[mi][nj][q] * ri;
      }
    }
  }
}

// ------- merge 16 sidecar partials per row: idx, rowinv, queue -------
__global__ __launch_bounds__(256) void rowstat_k(
    const float* __restrict__ ssum, const unsigned long long* __restrict__ sk1,
    const unsigned long long* __restrict__ sk2, int* __restrict__ idx,
    float* __restrict__ rowinv, int* __restrict__ queue,
    int* __restrict__ qcount, int baseRow) {
  const int row = blockIdx.x * 16 + (threadIdx.x >> 4);
  const int p = threadIdx.x & 15;
  const size_t sp = (size_t)row * 16 + p;
  float sum = ssum[sp];
  unsigned long long k1 = sk1[sp], k2 = sk2[sp];
  #pragma unroll
  for (int off = 1; off < 16; off <<= 1) {
    const unsigned long long o1 = __shfl_xor(k1, off);
    const unsigned long long o2 = __shfl_xor(k2, off);
    sum += __shfl_xor(sum, off);
    merge2(k1, k2, o1, o2);
  }
  if (p == 0) {
    const int tok = baseRow + row;
    idx[tok] = unpackcol(k1);
    rowinv[row] = 1.0f / sum;
    if (unpackval(k1) - unpackval(k2) < TAU_BF) {
      int slot = atomicAdd(qcount, 1);
      if (slot < QCAP) queue[slot] = tok;
    }
  }
}

// ------- gather queued tokens' normalized rows -> compact hi/lo matrix -------
__global__ __launch_bounds__(256) void gather_prep_k(
    const int* __restrict__ queue, const int* __restrict__ qcount,
    const float* __restrict__ inp, const float* __restrict__ inv_n,
    unsigned short* __restrict__ Qh, unsigned short* __restrict__ Ql) {
  const int w = blockIdx.x * 4 + (threadIdx.x >> 6);
  const int lane = threadIdx.x & 63;
  int cnt = *qcount; if (cnt > QCAP) cnt = QCAP;
  if (w >= cnt) return;
  const int tok = queue[w];
  const float rn = inv_n[tok];
  const float* x = inp + (size_t)tok * FDIM;
  #pragma unroll
  for (int h = 0; h < 2; ++h) {
    float4 xv = *(const float4*)(x + h * 256 + lane * 4);
    float vv[4] = {xv.x, xv.y, xv.z, xv.w};
    ushort4 hs, lo;
    #pragma unroll
    for (int q = 0; q < 4; ++q) {
      float v = vv[q] * rn;
      unsigned short hb = f2h(v);
      ((unsigned short*)&hs)[q] = hb;
      ((unsigned short*)&lo)[q] = f2h(v - h2f(hb));
    }
    const size_t e = (size_t)w * FDIM + h * 256 + lane * 4;
    *(ushort4*)(Qh + e) = hs;
    *(ushort4*)(Ql + e) = lo;
  }
}

// ------- level-2: full-row top-2 on split-S; fp64 pair-decide; write idx -------
__global__ __launch_bounds__(256) void refine2_k(
    const int* __restrict__ queue, const int* __restrict__ qcount,
    const float* __restrict__ Sref, const float* __restrict__ inp,
    const float* __restrict__ mem, int* __restrict__ idx) {
  const int w = blockIdx.x * 4 + (threadIdx.x >> 6);
  const int lane = threadIdx.x & 63;
  int cnt = *qcount; if (cnt > QCAP) cnt = QCAP;
  if (w >= cnt) return;
  const int tok = queue[w];
  const float* srow = Sref + (size_t)w * MDIM;
  float m1 = -3.4e38f, m2 = -3.4e38f;
  int i1 = 0x7fffffff, i2 = 0x7fffffff;
  #pragma unroll
  for (int i = 0; i < 8; ++i) {
    const float4 vv = *(const float4*)(srow + i * 256 + lane * 4);
    const float xs[4] = {vv.x, vv.y, vv.z, vv.w};
    #pragma unroll
    for (int q = 0; q < 4; ++q) {
      const float x = xs[q];
      const int ii = i * 256 + lane * 4 + q;
      if (x > m1 || (x == m1 && ii < i1)) { m2 = m1; i2 = i1; m1 = x; i1 = ii; }
      else if (x > m2 || (x == m2 && ii < i2)) { m2 = x; i2 = ii; }
    }
  }
  #pragma unroll
  for (int off = 1; off < 64; off <<= 1) {
    const float n1 = __shfl_xor(m1, off), n2 = __shfl_xor(m2, off);
    const int j1 = __shfl_xor(i1, off), j2 = __shfl_xor(i2, off);
    if (n1 > m1 || (n1 == m1 && j1 < i1)) {
      if (m1 > n2 || (m1 == n2 && i1 < j2)) { m2 = m1; i2 = i1; }
      else { m2 = n2; i2 = j2; }
      m1 = n1; i1 = j1;
    } else if (n1 > m2 || (n1 == m2 && j1 < i2)) { m2 = n1; i2 = j1; }
  }
  int pick = i1;
  if (m1 - m2 < TAU_SP) {
    const int a = (i1 < i2) ? i1 : i2, b = (i1 < i2) ? i2 : i1;
    const float* x = inp + (size_t)tok * FDIM;
    const float* ma = mem + (size_t)a * FDIM;
    const float* mb = mem + (size_t)b * FDIM;
    double da = 0, db = 0, na = 0, nb = 0;
    #pragma unroll
    for (int j = 0; j < 8; ++j) {
      const int e = lane * 8 + j;
      const double xv = x[e], av = ma[e], bv = mb[e];
      da += xv * av; na += av * av;
      db += xv * bv; nb += bv * bv;
    }
    #pragma unroll
    for (int off = 1; off < 64; off <<= 1) {
      da += __shfl_xor(da, off); na += __shfl_xor(na, off);
      db += __shfl_xor(db, off); nb += __shfl_xor(nb, off);
    }
    const double d1 = da / sqrt(fmax(na, 1e-12));
    const double d2 = db / sqrt(fmax(nb, 1e-12));
    if (d2 > d1) pick = b;
    else pick = a;
  }
  if (lane == 0) idx[tok] = pick;
}

// ------- deterministic segment-sum: one block per code, no atomics -------
__global__ __launch_bounds__(256) void segsum_k(
    const int* __restrict__ idx, const float* __restrict__ inp,
    const float* __restrict__ inv_n, float* __restrict__ updates) {
  __shared__ int lst[256];
  __shared__ int lcnt;
  const int m = blockIdx.x;
  const int t = threadIdx.x;
  float a0 = 0.f, a1 = 0.f;
  for (int base = 0; base < N_TOK; base += 4096) {
    if (t == 0) lcnt = 0;
    __syncthreads();
    #pragma unroll
    for (int u = 0; u < 4; ++u) {
      const int off4 = (u * 256 + t) * 4;
      const int4 v = *(const int4*)&idx[base + off4];
      if (v.x == m) { int p = atomicAdd(&lcnt, 1); if (p < 256) lst[p] = base + off4 + 0; }
      if (v.y == m) { int p = atomicAdd(&lcnt, 1); if (p < 256) lst[p] = base + off4 + 1; }
      if (v.z == m) { int p = atomicAdd(&lcnt, 1); if (p < 256) lst[p] = base + off4 + 2; }
      if (v.w == m) { int p = atomicAdd(&lcnt, 1); if (p < 256) lst[p] = base + off4 + 3; }
    }
    __syncthreads();
    int c = lcnt; if (c > 256) c = 256;
    if (t == 0 && c > 1) {
      for (int i = 1; i < c; ++i) {
        int key = lst[i], j = i - 1;
        while (j >= 0 && lst[j] > key) { lst[j + 1] = lst[j]; --j; }
        lst[j + 1] = key;
      }
    }
    __syncthreads();
    for (int i = 0; i < c; ++i) {
      const int tok = lst[i];
      const float rn = inv_n[tok];
      const float2 xv = *(const float2*)&inp[(size_t)tok * FDIM + t * 2];
      a0 += xv.x * rn; a1 += xv.y * rn;
    }
    __syncthreads();
  }
  *(float2*)&updates[(size_t)m * FDIM + t * 2] = make_float2(a0, a1);
}

// ---------------- final blend (fp32 out) ----------------
__global__ __launch_bounds__(256) void final_update_k(
    const float* __restrict__ mem, const float* __restrict__ upd,
    float* __restrict__ out) {
  const size_t i = ((size_t)blockIdx.x * 256 + threadIdx.x) * 4;
  float4 m = *(const float4*)(mem + i);
  float4 u = *(const float4*)(upd + i);
  float4 r;
  r.x = m.x * 0.9f + u.x * 0.1f;
  r.y = m.y * 0.9f + u.y * 0.1f;
  r.z = m.z * 0.9f + u.z * 0.1f;
  r.w = m.w * 0.9f + u.w * 0.1f;
  *(float4*)(out + i) = r;
}

extern "C" void kernel_launch(void* const* d_in, const int* in_sizes, int n_in,
                              void* d_out, int out_size, void* d_ws, size_t ws_size,
                              hipStream_t stream) {
  const float* inputs = (const float*)d_in[0];
  const float* memory = (const float*)d_in[1];
  if (n_in >= 2 && in_sizes[0] != N_TOK * FDIM) {  // order guard
    inputs = (const float*)d_in[1];
    memory = (const float*)d_in[0];
  }
  float* out_mu = (float*)d_out;                       // [N][F] fp32
  float* out_um = out_mu + (size_t)N_TOK * FDIM;       // [M][F] fp32

  char* base = (char*)d_ws;
  size_t off = 0;
  auto take = [&](size_t bytes) -> char* {
    char* p = base + off;
    off = (off + bytes + 255) & ~(size_t)255;
    return p;
  };
  unsigned short* Bh = (unsigned short*)take((size_t)MDIM * FDIM * 2);
  unsigned short* Bl = (unsigned short*)take((size_t)MDIM * FDIM * 2);
  unsigned short* Bt = (unsigned short*)take((size_t)MDIM * FDIM * 2);
  float* inv_n = (float*)take((size_t)N_TOK * 4);
  float* updates = (float*)take((size_t)MDIM * FDIM * 4);
  int* idx = (int*)take((size_t)N_TOK * 4);
  int* queue = (int*)take((size_t)QCAP * 4);
  int* qcount = (int*)take(256);
  unsigned short* Qh = (unsigned short*)take((size_t)QCAP * FDIM * 2);
  unsigned short* Ql = (unsigned short*)take((size_t)QCAP * FDIM * 2);
  float* Sref = (float*)take((size_t)QCAP * MDIM * 4);
  const size_t fixed = off;

  // per-token: Ah 1024 + P 4096 + sidecar 16*(4+8+8)=320 + rowinv 4
  int chunkT = 65536;  // single pass if ws allows
  while (chunkT > 2048 && fixed + (size_t)chunkT * 5700 + 8192 > ws_size)
    chunkT >>= 1;
  if (fixed + (size_t)chunkT * 5700 + 8192 > ws_size) return;  // ws too small

  unsigned short* Ah = (unsigned short*)take((size_t)chunkT * FDIM * 2);
  unsigned short* Pbuf = (unsigned short*)take((size_t)chunkT * MDIM * 2);
  float* ssum = (float*)take((size_t)chunkT * 16 * 4);
  unsigned long long* sk1 = (unsigned long long*)take((size_t)chunkT * 16 * 8);
  unsigned long long* sk2 = (unsigned long long*)take((size_t)chunkT * 16 * 8);
  float* rowinv = (float*)take((size_t)chunkT * 4);

  prep_memory_k<<<MDIM, 64, 0, stream>>>(memory, Bh, Bl, qcount);
  transpose_k<<<dim3(MDIM / 32, FDIM / 32), 256, 0, stream>>>(Bh, Bt);

  const int nby = chunkT / 128;
  for (int baseRow = 0; baseRow < N_TOK; baseRow += chunkT) {
    prep_a_k<<<chunkT / 4, 256, 0, stream>>>(inputs, inv_n, Ah, baseRow);
    // GEMM1 (128^2 dbuf + fused exp/sidecar epilogue)
    gemm_bt_k<1, false, true><<<16 * nby, 256, 0, stream>>>(
        Ah, nullptr, Bh, nullptr, (void*)Pbuf, MDIM, FDIM, 4, nullptr,
        ssum, sk1, sk2);
    rowstat_k<<<chunkT / 16, 256, 0, stream>>>(
        ssum, sk1, sk2, idx, rowinv, queue, qcount, baseRow);
    // GEMM2 (8-phase 256^2, K=2048): out = (P * Bt^T) * rowinv
    gemm8p2_k<<<(chunkT / 256) * 2, 512, 0, stream>>>(
        Pbuf, Bt, out_mu + (size_t)baseRow * FDIM, FDIM, MDIM, rowinv);
  }
  // two-level argmax refine: gather ambiguous rows, split-GEMM, decide idx
  gather_prep_k<<<QCAP / 4, 256, 0, stream>>>(queue, qcount, inputs, inv_n, Qh, Ql);
  gemm_bt_k<0, true, false><<<16 * (QCAP / 128), 256, 0, stream>>>(
      Qh, Ql, Bh, Bl, (void*)Sref, MDIM, FDIM, 4, qcount,
      nullptr, nullptr, nullptr);
  refine2_k<<<QCAP / 4, 256, 0, stream>>>(queue, qcount, Sref, inputs, memory, idx);
  // deterministic segment-sum (no atomics), then blend
  segsum_k<<<MDIM, 256, 0, stream>>>(idx, inputs, inv_n, updates);
  final_update_k<<<(MDIM * FDIM / 4) / 256, 256, 0, stream>>>(memory, updates, out_um);
}